// Round 1
// baseline (953.471 us; speedup 1.0000x reference)
//
#include <hip/hip_runtime.h>
#include <hip/hip_bf16.h>

// ChildSumTreeLSTM on complete binary tree, heap layout (children of n: 2n+1, 2n+2).
// DEPTH=17, N=2^17-1=131071, DIM=128 everywhere.
// Round 1: fp32 baseline. Pre-transpose weights -> WT[k][h] in ws, then one
// kernel per level (bottom-up), plus final projection.
// ws layout (floats): [9 x 16384 transposed weights][h: N*128][c: N*128] ~= 135 MB.

#define DEPTH 17
#define NTREE ((1 << DEPTH) - 1)
#define DIM 128

struct Ptrs9 { const float* p[9]; };

// dst[m][k*128+h] = src[m][h*128+k]; slot order: Wi,Wf,Wo,Wu,Ui,Uf,Uo,Uu,Wp
__global__ __launch_bounds__(256) void transpose_w(Ptrs9 srcs, float* __restrict__ dst) {
    int m = blockIdx.x >> 6;
    int e = ((blockIdx.x & 63) << 8) + threadIdx.x;  // 0..16383
    int k = e >> 7, h = e & 127;
    dst[m * 16384 + k * 128 + h] = srcs.p[m][h * 128 + k];
}

__device__ __forceinline__ float sigm(float v) { return 1.0f / (1.0f + __expf(-v)); }

// Leaf level (d=16): i=sig(li), o=sig(lo), u=tanh(lu); c=i*u; h=o*tanh(c).
// 16 nodes/block, 256 threads: thread = (grp in {0,1} -> 8 nodes, channel h).
__global__ __launch_bounds__(256) void leaf_kernel(
    const float* __restrict__ x, const float* __restrict__ wt,
    const float* __restrict__ bWi, const float* __restrict__ bWo, const float* __restrict__ bWu,
    float* __restrict__ hbuf, float* __restrict__ cbuf) {
    __shared__ float xs[16][DIM];
    const int tid = threadIdx.x;
    const int h = tid & 127;
    const int grp = tid >> 7;
    const int s = (1 << (DEPTH - 1)) - 1;  // 65535
    const int nbase = s + blockIdx.x * 16;

    const float4* src = (const float4*)(x + (size_t)nbase * DIM);
    float4* dst = (float4*)&xs[0][0];
#pragma unroll
    for (int i = 0; i < 2; ++i) dst[tid + 256 * i] = src[tid + 256 * i];
    __syncthreads();

    const float* WiT = wt + 0 * 16384;
    const float* WoT = wt + 2 * 16384;
    const float* WuT = wt + 3 * 16384;

    float ai[8], ao[8], au[8];
    const float bi = bWi[h], bo = bWo[h], bu = bWu[h];
#pragma unroll
    for (int j = 0; j < 8; ++j) { ai[j] = bi; ao[j] = bo; au[j] = bu; }

    for (int k = 0; k < DIM; k += 4) {
        float wi[4], wo[4], wu[4];
#pragma unroll
        for (int q = 0; q < 4; ++q) {
            const int off = (k + q) * DIM + h;
            wi[q] = WiT[off]; wo[q] = WoT[off]; wu[q] = WuT[off];
        }
#pragma unroll
        for (int j = 0; j < 8; ++j) {
            float4 xv = *(const float4*)&xs[grp * 8 + j][k];
            const float* xp = (const float*)&xv;
#pragma unroll
            for (int q = 0; q < 4; ++q) {
                ai[j] += xp[q] * wi[q];
                ao[j] += xp[q] * wo[q];
                au[j] += xp[q] * wu[q];
            }
        }
    }
#pragma unroll
    for (int j = 0; j < 8; ++j) {
        const int gn = nbase + grp * 8 + j;
        float iv = sigm(ai[j]);
        float ov = sigm(ao[j]);
        float uv = tanhf(au[j]);
        float cv = iv * uv;
        cbuf[(size_t)gn * DIM + h] = cv;
        hbuf[(size_t)gn * DIM + h] = ov * tanhf(cv);
    }
}

// Internal levels. JPT = nodes per thread; block 256 = 2 groups x 128 channels,
// NPB = 2*JPT nodes per block. Children rows of a node block are contiguous.
template <int JPT>
__global__ __launch_bounds__(256) void internal_kernel(
    const float* __restrict__ x, const float* __restrict__ wt,
    const float* __restrict__ bWi, const float* __restrict__ bUi,
    const float* __restrict__ bWf, const float* __restrict__ bUf,
    const float* __restrict__ bWo, const float* __restrict__ bUo,
    const float* __restrict__ bWu, const float* __restrict__ bUu,
    float* __restrict__ hbuf, float* __restrict__ cbuf, int s, int cnt) {
    constexpr int NPB = 2 * JPT;
    __shared__ float xs[NPB][DIM];
    __shared__ float hs[2 * NPB][DIM];
    const int tid = threadIdx.x;
    const int h = tid & 127;
    const int grp = tid >> 7;
    const int nb_loc = blockIdx.x * NPB;
    const int valid = (cnt - nb_loc) < NPB ? (cnt - nb_loc) : NPB;
    const int nbase = s + nb_loc;
    const int cbase = 2 * nbase + 1;  // children global base, 2*valid contiguous rows

    {
        const float4* src = (const float4*)(x + (size_t)nbase * DIM);
        float4* dst = (float4*)&xs[0][0];
        for (int i = tid; i < valid * 32; i += 256) dst[i] = src[i];
    }
    {
        const float4* src = (const float4*)(hbuf + (size_t)cbase * DIM);
        float4* dst = (float4*)&hs[0][0];
        for (int i = tid; i < 2 * valid * 32; i += 256) dst[i] = src[i];
    }
    __syncthreads();

    const float* WiT = wt + 0 * 16384;
    const float* WfT = wt + 1 * 16384;
    const float* WoT = wt + 2 * 16384;
    const float* WuT = wt + 3 * 16384;
    const float* UiT = wt + 4 * 16384;
    const float* UfT = wt + 5 * 16384;
    const float* UoT = wt + 6 * 16384;
    const float* UuT = wt + 7 * 16384;

    float ai[JPT], af[JPT], ao[JPT], au[JPT], afl[JPT], afr[JPT];
    const float bi = bWi[h] + bUi[h];
    const float bf = bWf[h] + bUf[h];
    const float bo = bWo[h] + bUo[h];
    const float bu = bWu[h] + bUu[h];
#pragma unroll
    for (int j = 0; j < JPT; ++j) {
        ai[j] = bi; af[j] = bf; ao[j] = bo; au[j] = bu;
        afl[j] = 0.0f; afr[j] = 0.0f;
    }

    for (int k = 0; k < DIM; k += 4) {
        float wi[4], wf[4], wo[4], wu[4], ui[4], uf[4], uo[4], uu[4];
#pragma unroll
        for (int q = 0; q < 4; ++q) {
            const int off = (k + q) * DIM + h;
            wi[q] = WiT[off]; wf[q] = WfT[off]; wo[q] = WoT[off]; wu[q] = WuT[off];
            ui[q] = UiT[off]; uf[q] = UfT[off]; uo[q] = UoT[off]; uu[q] = UuT[off];
        }
#pragma unroll
        for (int j = 0; j < JPT; ++j) {
            const int n = grp * JPT + j;
            float4 xv = *(const float4*)&xs[n][k];
            float4 hl4 = *(const float4*)&hs[2 * n][k];
            float4 hr4 = *(const float4*)&hs[2 * n + 1][k];
            const float* xp = (const float*)&xv;
            const float* lp = (const float*)&hl4;
            const float* rp = (const float*)&hr4;
#pragma unroll
            for (int q = 0; q < 4; ++q) {
                const float xq = xp[q], hlq = lp[q], hrq = rp[q];
                const float hsq = hlq + hrq;
                ai[j] += xq * wi[q] + hsq * ui[q];
                af[j] += xq * wf[q];
                ao[j] += xq * wo[q] + hsq * uo[q];
                au[j] += xq * wu[q] + hsq * uu[q];
                afl[j] += hlq * uf[q];
                afr[j] += hrq * uf[q];
            }
        }
    }

#pragma unroll
    for (int j = 0; j < JPT; ++j) {
        const int n = grp * JPT + j;
        if (n < valid) {
            const int gn = nbase + n;
            float iv = sigm(ai[j]);
            float ov = sigm(ao[j]);
            float uv = tanhf(au[j]);
            float fl = sigm(af[j] + afl[j]);
            float fr = sigm(af[j] + afr[j]);
            float cl = cbuf[(size_t)(2 * gn + 1) * DIM + h];
            float cr = cbuf[(size_t)(2 * gn + 2) * DIM + h];
            float cv = iv * uv + fl * cl + fr * cr;
            cbuf[(size_t)gn * DIM + h] = cv;
            hbuf[(size_t)gn * DIM + h] = ov * tanhf(cv);
        }
    }
}

// out = h_root @ Wp.T + bWp  (WpT[k][o] layout)
__global__ __launch_bounds__(128) void proj_kernel(
    const float* __restrict__ hbuf, const float* __restrict__ wpT,
    const float* __restrict__ bWp, float* __restrict__ out) {
    const int h = threadIdx.x;
    __shared__ float hr[DIM];
    hr[h] = hbuf[h];
    __syncthreads();
    float acc = bWp[h];
    for (int k = 0; k < DIM; ++k) acc += hr[k] * wpT[k * DIM + h];
    out[h] = acc;
}

extern "C" void kernel_launch(void* const* d_in, const int* in_sizes, int n_in,
                              void* d_out, int out_size, void* d_ws, size_t ws_size,
                              hipStream_t stream) {
    const float* x   = (const float*)d_in[0];
    // d_in[1] = edge_index (implicit heap layout; unused)
    const float* Wi  = (const float*)d_in[2];  const float* bWi = (const float*)d_in[3];
    const float* Ui  = (const float*)d_in[4];  const float* bUi = (const float*)d_in[5];
    const float* Wf  = (const float*)d_in[6];  const float* bWf = (const float*)d_in[7];
    const float* Uf  = (const float*)d_in[8];  const float* bUf = (const float*)d_in[9];
    const float* Wo  = (const float*)d_in[10]; const float* bWo = (const float*)d_in[11];
    const float* Uo  = (const float*)d_in[12]; const float* bUo = (const float*)d_in[13];
    const float* Wu  = (const float*)d_in[14]; const float* bWu = (const float*)d_in[15];
    const float* Uu  = (const float*)d_in[16]; const float* bUu = (const float*)d_in[17];
    const float* Wp  = (const float*)d_in[18]; const float* bWp = (const float*)d_in[19];

    float* ws   = (float*)d_ws;
    float* wt   = ws;                         // 9*16384 floats
    float* hbuf = ws + 9 * 16384;             // N*128
    float* cbuf = hbuf + (size_t)NTREE * DIM; // N*128

    Ptrs9 srcs;
    srcs.p[0] = Wi; srcs.p[1] = Wf; srcs.p[2] = Wo; srcs.p[3] = Wu;
    srcs.p[4] = Ui; srcs.p[5] = Uf; srcs.p[6] = Uo; srcs.p[7] = Uu;
    srcs.p[8] = Wp;
    transpose_w<<<9 * 64, 256, 0, stream>>>(srcs, wt);

    // d = 16 (leaves): 65536 nodes
    leaf_kernel<<<(1 << (DEPTH - 1)) / 16, 256, 0, stream>>>(x, wt, bWi, bWo, bWu, hbuf, cbuf);

    for (int d = DEPTH - 2; d >= 0; --d) {
        const int s = (1 << d) - 1;
        const int cnt = 1 << d;
        if (cnt >= 4096) {
            internal_kernel<8><<<cnt / 16, 256, 0, stream>>>(
                x, wt, bWi, bUi, bWf, bUf, bWo, bUo, bWu, bUu, hbuf, cbuf, s, cnt);
        } else if (cnt >= 256) {
            internal_kernel<4><<<cnt / 8, 256, 0, stream>>>(
                x, wt, bWi, bUi, bWf, bUf, bWo, bUo, bWu, bUu, hbuf, cbuf, s, cnt);
        } else {
            internal_kernel<1><<<(cnt + 1) / 2, 256, 0, stream>>>(
                x, wt, bWi, bUi, bWf, bUf, bWo, bUo, bWu, bUu, hbuf, cbuf, s, cnt);
        }
    }

    proj_kernel<<<1, 128, 0, stream>>>(hbuf, wt + 8 * 16384, bWp, (float*)d_out);
}

// Round 2
// 542.019 us; speedup vs baseline: 1.7591x; 1.7591x over previous
//
#include <hip/hip_runtime.h>
#include <hip/hip_bf16.h>

// ChildSumTreeLSTM, complete binary tree heap layout (children of n: 2n+1, 2n+2).
// R2: bf16 MFMA per level. B4 = [W/2 | U] (f-gate W not halved), K=256, N=512
// gate order [i,o,u,f]. Child row r computes [x_parent; h_child] @ B4^T; the
// fused epilogue sums row pairs in-lane (C/D rows 4q+r live in regs) so the
// whole gate/c/h update is register-local. No LDS. c kept fp32, x/h bf16.

#define DEPTH 17
#define NTREE ((1 << DEPTH) - 1)  // 131071
#define DIM 128

typedef __attribute__((ext_vector_type(8))) short short8;
typedef __attribute__((ext_vector_type(4))) float float4v;

__device__ __forceinline__ float sigm(float v) { return 1.0f / (1.0f + __expf(-v)); }

__device__ __forceinline__ unsigned short f2bf(float f) {
    union { float f; unsigned u; } a; a.f = f;
    unsigned u = a.u;
    return (unsigned short)((u + 0x7fffu + ((u >> 16) & 1u)) >> 16);  // RNE
}
__device__ __forceinline__ float bf2f(unsigned short s) {
    union { unsigned u; float f; } a; a.u = ((unsigned)s) << 16;
    return a.f;
}

struct WPtrs {
    const float* W[4];  const float* U[4];
    const float* bW[4]; const float* bU[4];
};

// B4[col 0..511][k 0..255] bf16: col = g*128 + c; k<128 -> W[g][c][k] * (g==3?1:0.5),
// k>=128 -> U[g][c][k-128]. biasWU = bW+bU, biasL = bW.
__global__ __launch_bounds__(256) void prep_kernel(WPtrs p, unsigned short* __restrict__ B4,
                                                   float* __restrict__ biasWU, float* __restrict__ biasL) {
    int row = blockIdx.x;       // 0..511
    int k = threadIdx.x;        // 0..255
    int g = row >> 7, c = row & 127;
    float v;
    if (k < 128) v = p.W[g][c * 128 + k] * (g == 3 ? 1.0f : 0.5f);
    else         v = p.U[g][c * 128 + (k - 128)];
    B4[row * 256 + k] = f2bf(v);
    if (k == 0) {
        biasWU[row] = p.bW[g][c] + p.bU[g][c];
        biasL[row]  = p.bW[g][c];
    }
}

__global__ __launch_bounds__(256) void convx_kernel(const float* __restrict__ x,
                                                    unsigned short* __restrict__ xbf, int n4) {
    int i = blockIdx.x * 256 + threadIdx.x;
    int stride = gridDim.x * 256;
    for (; i < n4; i += stride) {
        float4 v = ((const float4*)x)[i];
        ushort4 o;
        o.x = f2bf(v.x); o.y = f2bf(v.y); o.z = f2bf(v.z); o.w = f2bf(v.w);
        ((ushort4*)xbf)[i] = o;
    }
}

// Block = 256 thr = 4 waves. Wave w owns cols [32w, 32w+32) of each gate.
// Internal: M = 32 child rows (16 nodes); Leaf: M = 32 node rows.
// acc[mtile][nt], nt = g*2 + t; col = g*128 + w*32 + t*16 + (lane&15).
template <bool LEAF>
__global__ __launch_bounds__(256) void level_kernel(
    const unsigned short* __restrict__ xbf, const unsigned short* __restrict__ B4,
    const float* __restrict__ bias, unsigned short* __restrict__ hbf,
    float* __restrict__ cbuf, int s, int cnt) {
    const int tid = threadIdx.x;
    const int w = tid >> 6;
    const int lane = tid & 63;
    const int L = lane & 15;
    const int q = lane >> 4;

    const int nbase = s + blockIdx.x * (LEAF ? 32 : 16);
    const int cb = 2 * nbase + 1;  // children base (internal)

    float4v acc[2][8];
#pragma unroll
    for (int m = 0; m < 2; ++m)
#pragma unroll
        for (int n = 0; n < 8; ++n) acc[m][n] = (float4v){0.f, 0.f, 0.f, 0.f};

    const unsigned short* bb = B4 + (size_t)(w * 32 + L) * 256 + q * 8;

    constexpr int KS = LEAF ? 4 : 8;
#pragma unroll
    for (int ks = 0; ks < KS; ++ks) {
        const int kk = ks * 32;            // position in B4's K (0..255)
        const int off = (kk & 127) + q * 8;  // within the 128-wide source row
        short8 a0, a1;
        if (LEAF) {
            a0 = *(const short8*)(xbf + (size_t)(nbase + L) * DIM + off);
            a1 = *(const short8*)(xbf + (size_t)(nbase + 16 + L) * DIM + off);
        } else if (kk < 128) {  // x part: parent rows, duplicated per child
            a0 = *(const short8*)(xbf + (size_t)(nbase + (L >> 1)) * DIM + off);
            a1 = *(const short8*)(xbf + (size_t)(nbase + 8 + (L >> 1)) * DIM + off);
        } else {                // h part: child rows (contiguous = next level)
            a0 = *(const short8*)(hbf + (size_t)(cb + L) * DIM + off);
            a1 = *(const short8*)(hbf + (size_t)(cb + 16 + L) * DIM + off);
        }
        const unsigned short* bp = bb + kk;
#pragma unroll
        for (int nt = 0; nt < 8; ++nt) {
            const int g = nt >> 1, t = nt & 1;
            short8 b = *(const short8*)(bp + (size_t)(g * 128 + t * 16) * 256);
            acc[0][nt] = __builtin_amdgcn_mfma_f32_16x16x32_bf16(a0, b, acc[0][nt], 0, 0, 0);
            acc[1][nt] = __builtin_amdgcn_mfma_f32_16x16x32_bf16(a1, b, acc[1][nt], 0, 0, 0);
        }
    }

    const int ch0 = w * 32 + L;
    if (LEAF) {
#pragma unroll
        for (int m = 0; m < 2; ++m)
#pragma unroll
            for (int r = 0; r < 4; ++r) {
                const int n = nbase + m * 16 + q * 4 + r;
#pragma unroll
                for (int t = 0; t < 2; ++t) {
                    const int ch = ch0 + t * 16;
                    // halved-W correction: logit = 2*acc + bW
                    float iv = sigm(2.f * acc[m][0 + t][r] + bias[ch]);
                    float ov = sigm(2.f * acc[m][2 + t][r] + bias[128 + ch]);
                    float uv = tanhf(2.f * acc[m][4 + t][r] + bias[256 + ch]);
                    float cv = iv * uv;
                    cbuf[(size_t)n * DIM + ch] = cv;
                    hbf[(size_t)n * DIM + ch] = f2bf(ov * tanhf(cv));
                }
            }
    } else {
        int valid = cnt - blockIdx.x * 16;
        if (valid > 16) valid = 16;
#pragma unroll
        for (int m = 0; m < 2; ++m)
#pragma unroll
            for (int e = 0; e < 2; ++e) {
                const int nl = m * 8 + q * 2 + e;
                if (nl < valid) {
                    const int n = nbase + nl;
                    const int r0 = 2 * e, r1 = 2 * e + 1;
#pragma unroll
                    for (int t = 0; t < 2; ++t) {
                        const int ch = ch0 + t * 16;
                        float iv = sigm(acc[m][0 + t][r0] + acc[m][0 + t][r1] + bias[ch]);
                        float ov = sigm(acc[m][2 + t][r0] + acc[m][2 + t][r1] + bias[128 + ch]);
                        float uv = tanhf(acc[m][4 + t][r0] + acc[m][4 + t][r1] + bias[256 + ch]);
                        float fl = sigm(acc[m][6 + t][r0] + bias[384 + ch]);
                        float fr = sigm(acc[m][6 + t][r1] + bias[384 + ch]);
                        float cl = cbuf[(size_t)(2 * n + 1) * DIM + ch];
                        float cr = cbuf[(size_t)(2 * n + 2) * DIM + ch];
                        float cv = iv * uv + fl * cl + fr * cr;
                        cbuf[(size_t)n * DIM + ch] = cv;
                        hbf[(size_t)n * DIM + ch] = f2bf(ov * tanhf(cv));
                    }
                }
            }
    }
}

// out = h_root @ Wp.T + bWp (h_root bf16, Wp fp32 row-major [o][k])
__global__ __launch_bounds__(128) void proj_kernel(const unsigned short* __restrict__ hbf,
                                                   const float* __restrict__ Wp,
                                                   const float* __restrict__ bWp,
                                                   float* __restrict__ out) {
    __shared__ float hr[DIM];
    const int o = threadIdx.x;
    hr[o] = bf2f(hbf[o]);
    __syncthreads();
    float acc = bWp[o];
    for (int k = 0; k < DIM; ++k) acc += hr[k] * Wp[o * DIM + k];
    out[o] = acc;
}

extern "C" void kernel_launch(void* const* d_in, const int* in_sizes, int n_in,
                              void* d_out, int out_size, void* d_ws, size_t ws_size,
                              hipStream_t stream) {
    const float* x   = (const float*)d_in[0];
    const float* Wi  = (const float*)d_in[2];  const float* bWi = (const float*)d_in[3];
    const float* Ui  = (const float*)d_in[4];  const float* bUi = (const float*)d_in[5];
    const float* Wf  = (const float*)d_in[6];  const float* bWf = (const float*)d_in[7];
    const float* Uf  = (const float*)d_in[8];  const float* bUf = (const float*)d_in[9];
    const float* Wo  = (const float*)d_in[10]; const float* bWo = (const float*)d_in[11];
    const float* Uo  = (const float*)d_in[12]; const float* bUo = (const float*)d_in[13];
    const float* Wu  = (const float*)d_in[14]; const float* bWu = (const float*)d_in[15];
    const float* Uu  = (const float*)d_in[16]; const float* bUu = (const float*)d_in[17];
    const float* Wp  = (const float*)d_in[18]; const float* bWp = (const float*)d_in[19];

    // ws layout (all 16B-aligned): B4 (512*256 bf16) | biasWU(512 f32) | biasL(512) |
    // cbuf (N*128 f32) | xbf (N*128 bf16) | hbf (N*128 bf16)  ~= 134.5 MB
    unsigned short* B4 = (unsigned short*)d_ws;
    float* biasWU = (float*)(B4 + 512 * 256);
    float* biasL  = biasWU + 512;
    float* cbuf   = biasL + 512;
    unsigned short* xbf = (unsigned short*)(cbuf + (size_t)NTREE * DIM);
    unsigned short* hbf = xbf + (size_t)NTREE * DIM;

    WPtrs p;
    p.W[0] = Wi; p.W[1] = Wo; p.W[2] = Wu; p.W[3] = Wf;
    p.U[0] = Ui; p.U[1] = Uo; p.U[2] = Uu; p.U[3] = Uf;
    p.bW[0] = bWi; p.bW[1] = bWo; p.bW[2] = bWu; p.bW[3] = bWf;
    p.bU[0] = bUi; p.bU[1] = bUo; p.bU[2] = bUu; p.bU[3] = bUf;

    prep_kernel<<<512, 256, 0, stream>>>(p, B4, biasWU, biasL);
    convx_kernel<<<4096, 256, 0, stream>>>(x, xbf, NTREE * DIM / 4);

    // leaves: d=16, 65536 nodes, 32 nodes/block
    level_kernel<true><<<(1 << (DEPTH - 1)) / 32, 256, 0, stream>>>(
        xbf, B4, biasL, hbf, cbuf, (1 << (DEPTH - 1)) - 1, 1 << (DEPTH - 1));

    for (int d = DEPTH - 2; d >= 0; --d) {
        const int s = (1 << d) - 1;
        const int cnt = 1 << d;
        const int grid = cnt >= 16 ? cnt / 16 : 1;
        level_kernel<false><<<grid, 256, 0, stream>>>(xbf, B4, biasWU, hbf, cbuf, s, cnt);
    }

    proj_kernel<<<1, 128, 0, stream>>>(hbf, Wp, bWp, (float*)d_out);
}

// Round 3
// 533.690 us; speedup vs baseline: 1.7866x; 1.0156x over previous
//
#include <hip/hip_runtime.h>
#include <hip/hip_bf16.h>

// ChildSumTreeLSTM, complete binary tree heap layout (children of n: 2n+1, 2n+2).
// R3: bf16 MFMA, 512-thread blocks (8 waves), wave owns ONE 16-col tile per gate
// (acc = 32 AGPR -> ~2x occupancy vs R2). Leaf skips f-gate. Levels d<=5 + final
// projection fused into a single-block kernel. B4 = [W/2 | U] (f-gate W unhalved),
// K=256, N=512, gate order [i,o,u,f]; child row r computes [x_par; h_child] @ B4^T,
// epilogue sums row pairs in-lane. c fp32, x/h bf16.

#define DEPTH 17
#define NTREE ((1 << DEPTH) - 1)  // 131071
#define DIM 128

typedef __attribute__((ext_vector_type(8))) short short8;
typedef __attribute__((ext_vector_type(4))) float float4v;

__device__ __forceinline__ float sigm(float v) { return 1.0f / (1.0f + __expf(-v)); }

__device__ __forceinline__ unsigned short f2bf(float f) {
    union { float f; unsigned u; } a; a.f = f;
    unsigned u = a.u;
    return (unsigned short)((u + 0x7fffu + ((u >> 16) & 1u)) >> 16);  // RNE
}
__device__ __forceinline__ float bf2f(unsigned short s) {
    union { unsigned u; float f; } a; a.u = ((unsigned)s) << 16;
    return a.f;
}

struct WPtrs {
    const float* W[4];  const float* U[4];
    const float* bW[4]; const float* bU[4];
};

// B4[col 0..511][k 0..255] bf16: col = g*128 + c; k<128 -> W[g][c][k] * (g==3?1:0.5),
// k>=128 -> U[g][c][k-128]. biasWU = bW+bU, biasL = bW.
__global__ __launch_bounds__(256) void prep_kernel(WPtrs p, unsigned short* __restrict__ B4,
                                                   float* __restrict__ biasWU, float* __restrict__ biasL) {
    int row = blockIdx.x;       // 0..511
    int k = threadIdx.x;        // 0..255
    int g = row >> 7, c = row & 127;
    float v;
    if (k < 128) v = p.W[g][c * 128 + k] * (g == 3 ? 1.0f : 0.5f);
    else         v = p.U[g][c * 128 + (k - 128)];
    B4[row * 256 + k] = f2bf(v);
    if (k == 0) {
        biasWU[row] = p.bW[g][c] + p.bU[g][c];
        biasL[row]  = p.bW[g][c];
    }
}

__global__ __launch_bounds__(256) void convx_kernel(const float* __restrict__ x,
                                                    unsigned short* __restrict__ xbf, int n4) {
    int i = blockIdx.x * 256 + threadIdx.x;
    int stride = gridDim.x * 256;
    for (; i < n4; i += stride) {
        float4 v = ((const float4*)x)[i];
        ushort4 o;
        o.x = f2bf(v.x); o.y = f2bf(v.y); o.z = f2bf(v.z); o.w = f2bf(v.w);
        ((ushort4*)xbf)[i] = o;
    }
}

// One internal 16-node tile (M = 32 child rows). Wave w owns within-gate cols
// [16w,16w+16). C/D: node-row = q*4+r (in-lane), col = L.
__device__ __forceinline__ void internal_tile(
    const unsigned short* __restrict__ xbf, const unsigned short* __restrict__ B4,
    const float* __restrict__ bias, unsigned short* __restrict__ hbf,
    float* __restrict__ cbuf, int nbase, int valid, int w, int L, int q) {
    const int cb = 2 * nbase + 1;

    float4v acc[2][4];
#pragma unroll
    for (int m = 0; m < 2; ++m)
#pragma unroll
        for (int g = 0; g < 4; ++g) acc[m][g] = (float4v){0.f, 0.f, 0.f, 0.f};

    const unsigned short* bb = B4 + (size_t)(w * 16 + L) * 256 + q * 8;

#pragma unroll
    for (int ks = 0; ks < 8; ++ks) {
        const int kk = ks * 32;
        const int off = (kk & 127) + q * 8;
        short8 a0, a1;
        if (kk < 128) {  // x part: parent rows, duplicated per child
            a0 = *(const short8*)(xbf + (size_t)(nbase + (L >> 1)) * DIM + off);
            a1 = *(const short8*)(xbf + (size_t)(nbase + 8 + (L >> 1)) * DIM + off);
        } else {         // h part: child rows (contiguous next level)
            a0 = *(const short8*)(hbf + (size_t)(cb + L) * DIM + off);
            a1 = *(const short8*)(hbf + (size_t)(cb + 16 + L) * DIM + off);
        }
        const unsigned short* bp = bb + kk;
#pragma unroll
        for (int g = 0; g < 4; ++g) {
            short8 b = *(const short8*)(bp + (size_t)(g * 128) * 256);
            acc[0][g] = __builtin_amdgcn_mfma_f32_16x16x32_bf16(a0, b, acc[0][g], 0, 0, 0);
            acc[1][g] = __builtin_amdgcn_mfma_f32_16x16x32_bf16(a1, b, acc[1][g], 0, 0, 0);
        }
    }

    const int ch = w * 16 + L;  // within-gate channel 0..127
#pragma unroll
    for (int m = 0; m < 2; ++m)
#pragma unroll
        for (int e = 0; e < 2; ++e) {
            const int nl = m * 8 + q * 2 + e;
            if (nl < valid) {
                const int n = nbase + nl;
                const int r0 = 2 * e, r1 = 2 * e + 1;
                float iv = sigm(acc[m][0][r0] + acc[m][0][r1] + bias[ch]);
                float ov = sigm(acc[m][1][r0] + acc[m][1][r1] + bias[128 + ch]);
                float uv = tanhf(acc[m][2][r0] + acc[m][2][r1] + bias[256 + ch]);
                float fl = sigm(acc[m][3][r0] + bias[384 + ch]);
                float fr = sigm(acc[m][3][r1] + bias[384 + ch]);
                float cl = cbuf[(size_t)(2 * n + 1) * DIM + ch];
                float cr = cbuf[(size_t)(2 * n + 2) * DIM + ch];
                float cv = iv * uv + fl * cl + fr * cr;
                cbuf[(size_t)n * DIM + ch] = cv;
                hbf[(size_t)n * DIM + ch] = f2bf(ov * tanhf(cv));
            }
        }
}

__global__ __launch_bounds__(512, 4) void internal_kernel(
    const unsigned short* __restrict__ xbf, const unsigned short* __restrict__ B4,
    const float* __restrict__ bias, unsigned short* __restrict__ hbf,
    float* __restrict__ cbuf, int s, int cnt) {
    const int tid = threadIdx.x;
    const int w = tid >> 6, lane = tid & 63, L = lane & 15, q = lane >> 4;
    const int nb = blockIdx.x * 16;
    int valid = cnt - nb; if (valid > 16) valid = 16;
    internal_tile(xbf, B4, bias, hbf, cbuf, s + nb, valid, w, L, q);
}

// Leaf: M = 32 node rows, K = 128 (x only), gates i,o,u (f skipped).
__global__ __launch_bounds__(512, 4) void leaf_kernel(
    const unsigned short* __restrict__ xbf, const unsigned short* __restrict__ B4,
    const float* __restrict__ bias, unsigned short* __restrict__ hbf,
    float* __restrict__ cbuf) {
    const int tid = threadIdx.x;
    const int w = tid >> 6, lane = tid & 63, L = lane & 15, q = lane >> 4;
    const int s = (1 << (DEPTH - 1)) - 1;  // 65535
    const int nbase = s + blockIdx.x * 32;

    float4v acc[2][3];
#pragma unroll
    for (int m = 0; m < 2; ++m)
#pragma unroll
        for (int g = 0; g < 3; ++g) acc[m][g] = (float4v){0.f, 0.f, 0.f, 0.f};

    const unsigned short* bb = B4 + (size_t)(w * 16 + L) * 256 + q * 8;

#pragma unroll
    for (int ks = 0; ks < 4; ++ks) {
        const int off = ks * 32 + q * 8;
        short8 a0 = *(const short8*)(xbf + (size_t)(nbase + L) * DIM + off);
        short8 a1 = *(const short8*)(xbf + (size_t)(nbase + 16 + L) * DIM + off);
        const unsigned short* bp = bb + ks * 32;
#pragma unroll
        for (int g = 0; g < 3; ++g) {
            short8 b = *(const short8*)(bp + (size_t)(g * 128) * 256);
            acc[0][g] = __builtin_amdgcn_mfma_f32_16x16x32_bf16(a0, b, acc[0][g], 0, 0, 0);
            acc[1][g] = __builtin_amdgcn_mfma_f32_16x16x32_bf16(a1, b, acc[1][g], 0, 0, 0);
        }
    }

    const int ch = w * 16 + L;
#pragma unroll
    for (int m = 0; m < 2; ++m)
#pragma unroll
        for (int r = 0; r < 4; ++r) {
            const int n = nbase + m * 16 + q * 4 + r;
            // halved-W correction: logit = 2*acc + bW
            float iv = sigm(2.f * acc[m][0][r] + bias[ch]);
            float ov = sigm(2.f * acc[m][1][r] + bias[128 + ch]);
            float uv = tanhf(2.f * acc[m][2][r] + bias[256 + ch]);
            float cv = iv * uv;
            cbuf[(size_t)n * DIM + ch] = cv;
            hbf[(size_t)n * DIM + ch] = f2bf(ov * tanhf(cv));
        }
}

// Levels d=5..0 + final projection, single block of 512 threads.
__global__ __launch_bounds__(512) void fused_small(
    const unsigned short* __restrict__ xbf, const unsigned short* __restrict__ B4,
    const float* __restrict__ bias, unsigned short* __restrict__ hbf,
    float* __restrict__ cbuf, const float* __restrict__ Wp,
    const float* __restrict__ bWp, float* __restrict__ out) {
    const int tid = threadIdx.x;
    const int w = tid >> 6, lane = tid & 63, L = lane & 15, q = lane >> 4;
    for (int d = 5; d >= 0; --d) {
        const int s = (1 << d) - 1, cnt = 1 << d;
        const int tiles = (cnt + 15) >> 4;
        for (int t = 0; t < tiles; ++t) {
            int valid = cnt - t * 16; if (valid > 16) valid = 16;
            internal_tile(xbf, B4, bias, hbf, cbuf, s + t * 16, valid, w, L, q);
        }
        __threadfence();
        __syncthreads();
    }
    if (tid < 128) {
        float acc = bWp[tid];
        for (int k = 0; k < DIM; ++k) acc += bf2f(hbf[k]) * Wp[tid * DIM + k];
        out[tid] = acc;
    }
}

extern "C" void kernel_launch(void* const* d_in, const int* in_sizes, int n_in,
                              void* d_out, int out_size, void* d_ws, size_t ws_size,
                              hipStream_t stream) {
    const float* x   = (const float*)d_in[0];
    const float* Wi  = (const float*)d_in[2];  const float* bWi = (const float*)d_in[3];
    const float* Ui  = (const float*)d_in[4];  const float* bUi = (const float*)d_in[5];
    const float* Wf  = (const float*)d_in[6];  const float* bWf = (const float*)d_in[7];
    const float* Uf  = (const float*)d_in[8];  const float* bUf = (const float*)d_in[9];
    const float* Wo  = (const float*)d_in[10]; const float* bWo = (const float*)d_in[11];
    const float* Uo  = (const float*)d_in[12]; const float* bUo = (const float*)d_in[13];
    const float* Wu  = (const float*)d_in[14]; const float* bWu = (const float*)d_in[15];
    const float* Uu  = (const float*)d_in[16]; const float* bUu = (const float*)d_in[17];
    const float* Wp  = (const float*)d_in[18]; const float* bWp = (const float*)d_in[19];

    // ws: B4 (512*256 bf16) | biasWU(512 f32) | biasL(512) | cbuf (N*128 f32) |
    //     xbf (N*128 bf16) | hbf (N*128 bf16)  ~= 134.5 MB
    unsigned short* B4 = (unsigned short*)d_ws;
    float* biasWU = (float*)(B4 + 512 * 256);
    float* biasL  = biasWU + 512;
    float* cbuf   = biasL + 512;
    unsigned short* xbf = (unsigned short*)(cbuf + (size_t)NTREE * DIM);
    unsigned short* hbf = xbf + (size_t)NTREE * DIM;

    WPtrs p;
    p.W[0] = Wi; p.W[1] = Wo; p.W[2] = Wu; p.W[3] = Wf;
    p.U[0] = Ui; p.U[1] = Uo; p.U[2] = Uu; p.U[3] = Uf;
    p.bW[0] = bWi; p.bW[1] = bWo; p.bW[2] = bWu; p.bW[3] = bWf;
    p.bU[0] = bUi; p.bU[1] = bUo; p.bU[2] = bUu; p.bU[3] = bUf;

    prep_kernel<<<512, 256, 0, stream>>>(p, B4, biasWU, biasL);
    convx_kernel<<<4096, 256, 0, stream>>>(x, xbf, NTREE * DIM / 4);

    leaf_kernel<<<(1 << (DEPTH - 1)) / 32, 512, 0, stream>>>(xbf, B4, biasL, hbf, cbuf);

    for (int d = DEPTH - 2; d >= 6; --d) {
        const int s = (1 << d) - 1;
        const int cnt = 1 << d;
        internal_kernel<<<cnt / 16, 512, 0, stream>>>(xbf, B4, biasWU, hbf, cbuf, s, cnt);
    }

    fused_small<<<1, 512, 0, stream>>>(xbf, B4, biasWU, hbf, cbuf, Wp, bWp, (float*)d_out);
}

// Round 4
// 347.892 us; speedup vs baseline: 2.7407x; 1.5341x over previous
//
#include <hip/hip_runtime.h>
#include <hip/hip_bf16.h>

// ChildSumTreeLSTM, complete binary tree heap layout (children of n: 2n+1, 2n+2).
// R4: B pre-swizzled into MFMA-fragment-stream order (every B load = one
// coalesced 1KB read), A staged via LDS (contiguous global rows -> coalesced),
// 32 nodes/block (4 m-tiles/wave) to amortize the B stream. x converted
// fp32->bf16 during staging (convx kernel deleted). B4 = [W/2 | U] (f-gate W
// unhalved), gate order [i,o,u,f]; child row r computes [x_par; h_child]@B^T,
// epilogue sums row pairs in-lane (C/D rows 4q+r in-lane). c fp32, h bf16.

#define DEPTH 17
#define NTREE ((1 << DEPTH) - 1)  // 131071
#define DIM 128
#define XSTR 136  // LDS row stride (elements); +8 pad -> 2-way bank aliasing max
#define HSTR 136

typedef __attribute__((ext_vector_type(8))) short short8;
typedef __attribute__((ext_vector_type(4))) float float4v;

__device__ __forceinline__ float sigm(float v) { return 1.0f / (1.0f + __expf(-v)); }

__device__ __forceinline__ unsigned short f2bf(float f) {
    union { float f; unsigned u; } a; a.f = f;
    unsigned u = a.u;
    return (unsigned short)((u + 0x7fffu + ((u >> 16) & 1u)) >> 16);  // RNE
}
__device__ __forceinline__ float bf2f(unsigned short s) {
    union { unsigned u; float f; } a; a.u = ((unsigned)s) << 16;
    return a.f;
}

struct WPtrs {
    const float* W[4];  const float* U[4];
    const float* bW[4]; const float* bU[4];
};

// Bsw[w][ks][g][lane][j]  (w:8, ks:8, g:4, lane:64, j:8)  = fragment-stream order.
// Element = B4[col = g*128 + w*16 + (lane&15)][k = ks*32 + (lane>>4)*8 + j],
// where B4 = [W * (g==3 ? 1 : 0.5) | U].
__global__ __launch_bounds__(256) void prep_kernel(WPtrs p, unsigned short* __restrict__ Bsw,
                                                   float* __restrict__ biasWU, float* __restrict__ biasL) {
    int idx = blockIdx.x * 256 + threadIdx.x;  // 0 .. 131071
    int j = idx & 7;
    int lane = (idx >> 3) & 63;
    int g = (idx >> 9) & 3;
    int ks = (idx >> 11) & 7;
    int w = idx >> 14;
    int L = lane & 15, q = lane >> 4;
    int c = w * 16 + L;
    int k = ks * 32 + q * 8 + j;
    float v = (k < 128) ? p.W[g][c * 128 + k] * (g == 3 ? 1.0f : 0.5f)
                        : p.U[g][c * 128 + (k - 128)];
    Bsw[idx] = f2bf(v);
    if (idx < 512) {
        int gg = idx >> 7, cc = idx & 127;
        biasWU[idx] = p.bW[gg][cc] + p.bU[gg][cc];
        biasL[idx]  = p.bW[gg][cc];
    }
}

// Stage `rows` fp32 x-rows (contiguous in global) into LDS as bf16, stride XSTR.
__device__ __forceinline__ void stage_x(const float* __restrict__ x, unsigned short* xs,
                                        int nbase, int rows) {
    for (int c = threadIdx.x; c < rows * 32; c += 512) {
        int row = c >> 5, j = c & 31;
        float4 v = *(const float4*)(x + (size_t)(nbase + row) * DIM + j * 4);
        ushort4 o;
        o.x = f2bf(v.x); o.y = f2bf(v.y); o.z = f2bf(v.z); o.w = f2bf(v.w);
        *(ushort4*)(xs + row * XSTR + j * 4) = o;
    }
}

// Stage 64 bf16 h-rows (contiguous: children of 32 consecutive nodes) into LDS.
__device__ __forceinline__ void stage_h(const unsigned short* __restrict__ hbf,
                                        unsigned short* hs, int cb) {
    for (int c = threadIdx.x; c < 1024; c += 512) {
        int row = c >> 4, j = c & 15;
        uint4 v = *(const uint4*)(hbf + (size_t)(cb + row) * DIM + j * 8);
        *(uint4*)(hs + row * HSTR + j * 8) = v;
    }
}

// One 32-node internal tile (64 child rows = 4 m-tiles). Wave w owns within-gate
// cols [16w,16w+16). C/D: child-row = 16m + q*4 + r (rows r in-lane), col = L.
__device__ __forceinline__ void internal_tile(
    const unsigned short* xs, const unsigned short* hs,
    const unsigned short* __restrict__ Bsw, const float* __restrict__ bias,
    unsigned short* __restrict__ hbf, float* __restrict__ cbuf,
    int nbase, int valid, int w, int L, int q, int lane) {
    float4v acc[4][4];
#pragma unroll
    for (int m = 0; m < 4; ++m)
#pragma unroll
        for (int g = 0; g < 4; ++g) acc[m][g] = (float4v){0.f, 0.f, 0.f, 0.f};

    const unsigned short* bw = Bsw + ((size_t)w << 14) + lane * 8;

#pragma unroll
    for (int ks = 0; ks < 8; ++ks) {
        const int kk = ks * 32;
        short8 b[4];
#pragma unroll
        for (int g = 0; g < 4; ++g)
            b[g] = *(const short8*)(bw + ((ks * 4 + g) << 9));
        short8 a[4];
        if (kk < 128) {  // x part: parent rows (lanes 2j,2j+1 broadcast)
#pragma unroll
            for (int m = 0; m < 4; ++m)
                a[m] = *(const short8*)(xs + (8 * m + (L >> 1)) * XSTR + kk + q * 8);
        } else {         // h part: child rows
#pragma unroll
            for (int m = 0; m < 4; ++m)
                a[m] = *(const short8*)(hs + (16 * m + L) * HSTR + (kk - 128) + q * 8);
        }
#pragma unroll
        for (int g = 0; g < 4; ++g)
#pragma unroll
            for (int m = 0; m < 4; ++m)
                acc[m][g] = __builtin_amdgcn_mfma_f32_16x16x32_bf16(a[m], b[g], acc[m][g], 0, 0, 0);
    }

    const int ch = w * 16 + L;  // within-gate channel
#pragma unroll
    for (int m = 0; m < 4; ++m)
#pragma unroll
        for (int e = 0; e < 2; ++e) {
            const int nl = 8 * m + q * 2 + e;
            if (nl < valid) {
                const int n = nbase + nl;
                const int r0 = 2 * e, r1 = 2 * e + 1;
                float iv = sigm(acc[m][0][r0] + acc[m][0][r1] + bias[ch]);
                float ov = sigm(acc[m][1][r0] + acc[m][1][r1] + bias[128 + ch]);
                float uv = tanhf(acc[m][2][r0] + acc[m][2][r1] + bias[256 + ch]);
                float fl = sigm(acc[m][3][r0] + bias[384 + ch]);
                float fr = sigm(acc[m][3][r1] + bias[384 + ch]);
                float cl = cbuf[(size_t)(2 * n + 1) * DIM + ch];
                float cr = cbuf[(size_t)(2 * n + 2) * DIM + ch];
                float cv = iv * uv + fl * cl + fr * cr;
                cbuf[(size_t)n * DIM + ch] = cv;
                hbf[(size_t)n * DIM + ch] = f2bf(ov * tanhf(cv));
            }
        }
}

__global__ __launch_bounds__(512, 4) void internal_kernel(
    const float* __restrict__ x, const unsigned short* __restrict__ Bsw,
    const float* __restrict__ bias, unsigned short* __restrict__ hbf,
    float* __restrict__ cbuf, int s) {
    __shared__ __align__(16) unsigned short xs[32 * XSTR];
    __shared__ __align__(16) unsigned short hs[64 * HSTR];
    const int tid = threadIdx.x;
    const int w = tid >> 6, lane = tid & 63, L = lane & 15, q = lane >> 4;
    const int nbase = s + blockIdx.x * 32;
    stage_x(x, xs, nbase, 32);
    stage_h(hbf, hs, 2 * nbase + 1);
    __syncthreads();
    internal_tile(xs, hs, Bsw, bias, hbf, cbuf, nbase, 32, w, L, q, lane);
}

// Leaf: 64 nodes/block, K=128 (x only), gates i,o,u (f skipped). logit = 2*acc + bW.
__global__ __launch_bounds__(512, 4) void leaf_kernel(
    const float* __restrict__ x, const unsigned short* __restrict__ Bsw,
    const float* __restrict__ bias, unsigned short* __restrict__ hbf,
    float* __restrict__ cbuf) {
    __shared__ __align__(16) unsigned short xs[64 * XSTR];
    const int tid = threadIdx.x;
    const int w = tid >> 6, lane = tid & 63, L = lane & 15, q = lane >> 4;
    const int nbase = ((1 << (DEPTH - 1)) - 1) + blockIdx.x * 64;
    stage_x(x, xs, nbase, 64);
    __syncthreads();

    float4v acc[4][3];
#pragma unroll
    for (int m = 0; m < 4; ++m)
#pragma unroll
        for (int g = 0; g < 3; ++g) acc[m][g] = (float4v){0.f, 0.f, 0.f, 0.f};

    const unsigned short* bw = Bsw + ((size_t)w << 14) + lane * 8;

#pragma unroll
    for (int ks = 0; ks < 4; ++ks) {
        short8 b[3];
#pragma unroll
        for (int g = 0; g < 3; ++g)
            b[g] = *(const short8*)(bw + ((ks * 4 + g) << 9));
        short8 a[4];
#pragma unroll
        for (int m = 0; m < 4; ++m)
            a[m] = *(const short8*)(xs + (16 * m + L) * XSTR + ks * 32 + q * 8);
#pragma unroll
        for (int g = 0; g < 3; ++g)
#pragma unroll
            for (int m = 0; m < 4; ++m)
                acc[m][g] = __builtin_amdgcn_mfma_f32_16x16x32_bf16(a[m], b[g], acc[m][g], 0, 0, 0);
    }

    const int ch = w * 16 + L;
#pragma unroll
    for (int m = 0; m < 4; ++m)
#pragma unroll
        for (int r = 0; r < 4; ++r) {
            const int n = nbase + 16 * m + q * 4 + r;
            float iv = sigm(2.f * acc[m][0][r] + bias[ch]);
            float ov = sigm(2.f * acc[m][1][r] + bias[128 + ch]);
            float uv = tanhf(2.f * acc[m][2][r] + bias[256 + ch]);
            float cv = iv * uv;
            cbuf[(size_t)n * DIM + ch] = cv;
            hbf[(size_t)n * DIM + ch] = f2bf(ov * tanhf(cv));
        }
}

// Levels d=5..0 + projection, single 512-thread block.
__global__ __launch_bounds__(512) void fused_small(
    const float* __restrict__ x, const unsigned short* __restrict__ Bsw,
    const float* __restrict__ bias, unsigned short* __restrict__ hbf,
    float* __restrict__ cbuf, const float* __restrict__ Wp,
    const float* __restrict__ bWp, float* __restrict__ out) {
    __shared__ __align__(16) unsigned short xs[32 * XSTR];
    __shared__ __align__(16) unsigned short hs[64 * HSTR];
    const int tid = threadIdx.x;
    const int w = tid >> 6, lane = tid & 63, L = lane & 15, q = lane >> 4;
    for (int d = 5; d >= 0; --d) {
        const int s = (1 << d) - 1, cnt = 1 << d;
        stage_x(x, xs, s, 32);
        stage_h(hbf, hs, 2 * s + 1);
        __syncthreads();
        internal_tile(xs, hs, Bsw, bias, hbf, cbuf, s, cnt, w, L, q, lane);
        __threadfence();
        __syncthreads();
    }
    if (tid < 128) {
        float acc = bWp[tid];
        for (int k = 0; k < DIM; ++k) acc += bf2f(hbf[k]) * Wp[tid * DIM + k];
        out[tid] = acc;
    }
}

extern "C" void kernel_launch(void* const* d_in, const int* in_sizes, int n_in,
                              void* d_out, int out_size, void* d_ws, size_t ws_size,
                              hipStream_t stream) {
    const float* x   = (const float*)d_in[0];
    const float* Wi  = (const float*)d_in[2];  const float* bWi = (const float*)d_in[3];
    const float* Ui  = (const float*)d_in[4];  const float* bUi = (const float*)d_in[5];
    const float* Wf  = (const float*)d_in[6];  const float* bWf = (const float*)d_in[7];
    const float* Uf  = (const float*)d_in[8];  const float* bUf = (const float*)d_in[9];
    const float* Wo  = (const float*)d_in[10]; const float* bWo = (const float*)d_in[11];
    const float* Uo  = (const float*)d_in[12]; const float* bUo = (const float*)d_in[13];
    const float* Wu  = (const float*)d_in[14]; const float* bWu = (const float*)d_in[15];
    const float* Uu  = (const float*)d_in[16]; const float* bUu = (const float*)d_in[17];
    const float* Wp  = (const float*)d_in[18]; const float* bWp = (const float*)d_in[19];

    // ws: Bsw (131072 bf16 = 256 KB) | biasWU(512 f32) | biasL(512 f32) |
    //     cbuf (N*128 f32 = 64 MB) | hbf (N*128 bf16 = 32 MB)
    unsigned short* Bsw = (unsigned short*)d_ws;
    float* biasWU = (float*)(Bsw + 131072);
    float* biasL  = biasWU + 512;
    float* cbuf   = biasL + 512;
    unsigned short* hbf = (unsigned short*)(cbuf + (size_t)NTREE * DIM);

    WPtrs p;
    p.W[0] = Wi; p.W[1] = Wo; p.W[2] = Wu; p.W[3] = Wf;
    p.U[0] = Ui; p.U[1] = Uo; p.U[2] = Uu; p.U[3] = Uf;
    p.bW[0] = bWi; p.bW[1] = bWo; p.bW[2] = bWu; p.bW[3] = bWf;
    p.bU[0] = bUi; p.bU[1] = bUo; p.bU[2] = bUu; p.bU[3] = bUf;

    prep_kernel<<<512, 256, 0, stream>>>(p, Bsw, biasWU, biasL);

    leaf_kernel<<<(1 << (DEPTH - 1)) / 64, 512, 0, stream>>>(x, Bsw, biasL, hbf, cbuf);

    for (int d = DEPTH - 2; d >= 6; --d) {
        const int s = (1 << d) - 1;
        const int cnt = 1 << d;
        internal_kernel<<<cnt / 32, 512, 0, stream>>>(x, Bsw, biasWU, hbf, cbuf, s);
    }

    fused_small<<<1, 512, 0, stream>>>(x, Bsw, biasWU, hbf, cbuf, Wp, bWp, (float*)d_out);
}

// Round 5
// 331.823 us; speedup vs baseline: 2.8734x; 1.0484x over previous
//
#include <hip/hip_runtime.h>
#include <hip/hip_bf16.h>

// ChildSumTreeLSTM, complete binary tree heap layout (children of n: 2n+1, 2n+2).
// R5: (a) fused tail (d=5..0 + projection) fully LDS-resident: no threadfence,
// no global h/c round-trips; (b) internal epilogue's child-c reads prefetched
// into registers right after the staging barrier (overlap with MFMA loop);
// (c) fast tanh/sigmoid (hw exp + fast div) replacing libm tanhf.
// B pre-swizzled in MFMA-fragment-stream order (Bsw: every B load = coalesced
// 1KB), A staged via LDS. B = [W/2 | U] (f-gate W unhalved), gates [i,o,u,f];
// child row r computes [x_par; h_child]@B^T, epilogue sums row pairs in-lane.
// c fp32, h bf16.

#define DEPTH 17
#define NTREE ((1 << DEPTH) - 1)  // 131071
#define DIM 128
#define XSTR 136  // LDS row strides (elements); pad -> <=2-way bank aliasing (free)
#define HSTR 136
#define CSTR 132

typedef __attribute__((ext_vector_type(8))) short short8;
typedef __attribute__((ext_vector_type(4))) float float4v;

__device__ __forceinline__ float sigm(float v) {
    return __fdividef(1.0f, 1.0f + __expf(-v));
}
__device__ __forceinline__ float ftanh(float v) {
    v = fminf(15.0f, fmaxf(-15.0f, v));
    float e = __expf(2.0f * v);
    return __fdividef(e - 1.0f, e + 1.0f);
}

__device__ __forceinline__ unsigned short f2bf(float f) {
    union { float f; unsigned u; } a; a.f = f;
    unsigned u = a.u;
    return (unsigned short)((u + 0x7fffu + ((u >> 16) & 1u)) >> 16);  // RNE
}
__device__ __forceinline__ float bf2f(unsigned short s) {
    union { unsigned u; float f; } a; a.u = ((unsigned)s) << 16;
    return a.f;
}

struct WPtrs {
    const float* W[4];  const float* U[4];
    const float* bW[4]; const float* bU[4];
};

// Bsw[w][ks][g][lane][j] (w:8, ks:8, g:4, lane:64, j:8) = fragment-stream order.
// Element = B4[col = g*128 + w*16 + (lane&15)][k = ks*32 + (lane>>4)*8 + j],
// where B4 = [W * (g==3 ? 1 : 0.5) | U].
__global__ __launch_bounds__(256) void prep_kernel(WPtrs p, unsigned short* __restrict__ Bsw,
                                                   float* __restrict__ biasWU, float* __restrict__ biasL) {
    int idx = blockIdx.x * 256 + threadIdx.x;  // 0 .. 131071
    int j = idx & 7;
    int lane = (idx >> 3) & 63;
    int g = (idx >> 9) & 3;
    int ks = (idx >> 11) & 7;
    int w = idx >> 14;
    int L = lane & 15, q = lane >> 4;
    int c = w * 16 + L;
    int k = ks * 32 + q * 8 + j;
    float v = (k < 128) ? p.W[g][c * 128 + k] * (g == 3 ? 1.0f : 0.5f)
                        : p.U[g][c * 128 + (k - 128)];
    Bsw[idx] = f2bf(v);
    if (idx < 512) {
        int gg = idx >> 7, cc = idx & 127;
        biasWU[idx] = p.bW[gg][cc] + p.bU[gg][cc];
        biasL[idx]  = p.bW[gg][cc];
    }
}

// Stage `rows` fp32 x-rows (contiguous in global) into LDS bf16, stride XSTR.
__device__ __forceinline__ void stage_x(const float* __restrict__ x, unsigned short* xs,
                                        int nbase, int rows) {
    for (int c = threadIdx.x; c < rows * 32; c += 512) {
        int row = c >> 5, j = c & 31;
        float4 v = *(const float4*)(x + (size_t)(nbase + row) * DIM + j * 4);
        ushort4 o;
        o.x = f2bf(v.x); o.y = f2bf(v.y); o.z = f2bf(v.z); o.w = f2bf(v.w);
        *(ushort4*)(xs + row * XSTR + j * 4) = o;
    }
}

// Stage 64 bf16 h-rows (contiguous) into LDS, stride HSTR.
__device__ __forceinline__ void stage_h(const unsigned short* __restrict__ hbf,
                                        unsigned short* hs, int cb) {
    for (int c = threadIdx.x; c < 1024; c += 512) {
        int row = c >> 4, j = c & 15;
        uint4 v = *(const uint4*)(hbf + (size_t)(cb + row) * DIM + j * 8);
        *(uint4*)(hs + row * HSTR + j * 8) = v;
    }
}

// Internal levels d=15..6: 32 nodes/block (64 child rows = 4 m-tiles/wave).
// Wave w owns within-gate cols [16w,16w+16). C/D child-row = 16m+q*4+r, col = L.
__global__ __launch_bounds__(512, 4) void internal_kernel(
    const float* __restrict__ x, const unsigned short* __restrict__ Bsw,
    const float* __restrict__ bias, unsigned short* __restrict__ hbf,
    float* __restrict__ cbuf, int s) {
    __shared__ __align__(16) unsigned short xs[32 * XSTR];
    __shared__ __align__(16) unsigned short hs[64 * HSTR];
    const int tid = threadIdx.x;
    const int w = tid >> 6, lane = tid & 63, L = lane & 15, q = lane >> 4;
    const int nbase = s + blockIdx.x * 32;
    const int ch = w * 16 + L;

    stage_x(x, xs, nbase, 32);
    stage_h(hbf, hs, 2 * nbase + 1);
    __syncthreads();

    // Prefetch child-c AFTER the barrier: results land during the MFMA loop,
    // consumed in the epilogue (removes the cold-L3 tail stall).
    float cl[8], cr[8];
#pragma unroll
    for (int m = 0; m < 4; ++m)
#pragma unroll
        for (int e = 0; e < 2; ++e) {
            const int n = nbase + 8 * m + 2 * q + e;
            cl[m * 2 + e] = cbuf[(size_t)(2 * n + 1) * DIM + ch];
            cr[m * 2 + e] = cbuf[(size_t)(2 * n + 2) * DIM + ch];
        }

    float4v acc[4][4];
#pragma unroll
    for (int m = 0; m < 4; ++m)
#pragma unroll
        for (int g = 0; g < 4; ++g) acc[m][g] = (float4v){0.f, 0.f, 0.f, 0.f};

    const unsigned short* bw = Bsw + ((size_t)w << 14) + lane * 8;

#pragma unroll
    for (int ks = 0; ks < 8; ++ks) {
        const int kk = ks * 32;
        short8 b[4];
#pragma unroll
        for (int g = 0; g < 4; ++g)
            b[g] = *(const short8*)(bw + ((ks * 4 + g) << 9));
        short8 a[4];
        if (kk < 128) {  // x part: parent rows (lanes 2j,2j+1 broadcast)
#pragma unroll
            for (int m = 0; m < 4; ++m)
                a[m] = *(const short8*)(xs + (8 * m + (L >> 1)) * XSTR + kk + q * 8);
        } else {         // h part: child rows
#pragma unroll
            for (int m = 0; m < 4; ++m)
                a[m] = *(const short8*)(hs + (16 * m + L) * HSTR + (kk - 128) + q * 8);
        }
#pragma unroll
        for (int g = 0; g < 4; ++g)
#pragma unroll
            for (int m = 0; m < 4; ++m)
                acc[m][g] = __builtin_amdgcn_mfma_f32_16x16x32_bf16(a[m], b[g], acc[m][g], 0, 0, 0);
    }

#pragma unroll
    for (int m = 0; m < 4; ++m)
#pragma unroll
        for (int e = 0; e < 2; ++e) {
            const int nl = 8 * m + q * 2 + e;
            const int n = nbase + nl;
            const int r0 = 2 * e, r1 = 2 * e + 1;
            float iv = sigm(acc[m][0][r0] + acc[m][0][r1] + bias[ch]);
            float ov = sigm(acc[m][1][r0] + acc[m][1][r1] + bias[128 + ch]);
            float uv = ftanh(acc[m][2][r0] + acc[m][2][r1] + bias[256 + ch]);
            float fl = sigm(acc[m][3][r0] + bias[384 + ch]);
            float fr = sigm(acc[m][3][r1] + bias[384 + ch]);
            float cv = iv * uv + fl * cl[m * 2 + e] + fr * cr[m * 2 + e];
            cbuf[(size_t)n * DIM + ch] = cv;
            hbf[(size_t)n * DIM + ch] = f2bf(ov * ftanh(cv));
        }
}

// Leaf: 64 nodes/block, K=128 (x only), gates i,o,u (f skipped). logit = 2*acc + bW.
__global__ __launch_bounds__(512, 4) void leaf_kernel(
    const float* __restrict__ x, const unsigned short* __restrict__ Bsw,
    const float* __restrict__ bias, unsigned short* __restrict__ hbf,
    float* __restrict__ cbuf) {
    __shared__ __align__(16) unsigned short xs[64 * XSTR];
    const int tid = threadIdx.x;
    const int w = tid >> 6, lane = tid & 63, L = lane & 15, q = lane >> 4;
    const int nbase = ((1 << (DEPTH - 1)) - 1) + blockIdx.x * 64;
    stage_x(x, xs, nbase, 64);
    __syncthreads();

    float4v acc[4][3];
#pragma unroll
    for (int m = 0; m < 4; ++m)
#pragma unroll
        for (int g = 0; g < 3; ++g) acc[m][g] = (float4v){0.f, 0.f, 0.f, 0.f};

    const unsigned short* bw = Bsw + ((size_t)w << 14) + lane * 8;

#pragma unroll
    for (int ks = 0; ks < 4; ++ks) {
        short8 b[3];
#pragma unroll
        for (int g = 0; g < 3; ++g)
            b[g] = *(const short8*)(bw + ((ks * 4 + g) << 9));
        short8 a[4];
#pragma unroll
        for (int m = 0; m < 4; ++m)
            a[m] = *(const short8*)(xs + (16 * m + L) * XSTR + ks * 32 + q * 8);
#pragma unroll
        for (int g = 0; g < 3; ++g)
#pragma unroll
            for (int m = 0; m < 4; ++m)
                acc[m][g] = __builtin_amdgcn_mfma_f32_16x16x32_bf16(a[m], b[g], acc[m][g], 0, 0, 0);
    }

    const int ch = w * 16 + L;
#pragma unroll
    for (int m = 0; m < 4; ++m)
#pragma unroll
        for (int r = 0; r < 4; ++r) {
            const int n = nbase + 16 * m + q * 4 + r;
            float iv = sigm(2.f * acc[m][0][r] + bias[ch]);
            float ov = sigm(2.f * acc[m][1][r] + bias[128 + ch]);
            float uv = ftanh(2.f * acc[m][2][r] + bias[256 + ch]);
            float cv = iv * uv;
            cbuf[(size_t)n * DIM + ch] = cv;
            hbf[(size_t)n * DIM + ch] = f2bf(ov * ftanh(cv));
        }
}

// Levels d=5..0 + projection, single 512-thread block, fully LDS-resident.
// Stages x(0..62) + h/c of nodes 63..126 once; ping-pong h/c in LDS.
__global__ __launch_bounds__(512) void fused_all(
    const float* __restrict__ x, const unsigned short* __restrict__ Bsw,
    const float* __restrict__ bias, const unsigned short* __restrict__ hbf,
    const float* __restrict__ cbuf, const float* __restrict__ Wp,
    const float* __restrict__ bWp, float* __restrict__ out) {
    __shared__ __align__(16) unsigned short xs[63 * XSTR];
    __shared__ __align__(16) unsigned short hping[2 * 64 * HSTR];
    __shared__ __align__(16) float cping[2 * 64 * CSTR];
    __shared__ float red[4][128];
    const int tid = threadIdx.x;
    const int w = tid >> 6, lane = tid & 63, L = lane & 15, q = lane >> 4;
    const int ch = w * 16 + L;

    stage_x(x, xs, 0, 63);
    stage_h(hbf, hping, 63);
    for (int c0 = tid; c0 < 64 * 32; c0 += 512) {
        int row = c0 >> 5, j = c0 & 31;
        float4 v = *(const float4*)(cbuf + (size_t)(63 + row) * DIM + j * 4);
        *(float4*)(cping + row * CSTR + j * 4) = v;
    }
    __syncthreads();

    int pp = 0;
    for (int d = 5; d >= 0; --d) {
        const int s = (1 << d) - 1, cnt = 1 << d;
        const unsigned short* hin = hping + pp * 64 * HSTR;
        const float* cin = cping + pp * 64 * CSTR;
        unsigned short* hout = hping + (1 - pp) * 64 * HSTR;
        float* cout = cping + (1 - pp) * 64 * CSTR;

        float4v acc[4][4];
#pragma unroll
        for (int m = 0; m < 4; ++m)
#pragma unroll
            for (int g = 0; g < 4; ++g) acc[m][g] = (float4v){0.f, 0.f, 0.f, 0.f};

        const unsigned short* bw = Bsw + ((size_t)w << 14) + lane * 8;

#pragma unroll
        for (int ks = 0; ks < 8; ++ks) {
            const int kk = ks * 32;
            short8 b[4];
#pragma unroll
            for (int g = 0; g < 4; ++g)
                b[g] = *(const short8*)(bw + ((ks * 4 + g) << 9));
            short8 a[4];
            if (kk < 128) {
#pragma unroll
                for (int m = 0; m < 4; ++m)
                    a[m] = *(const short8*)(xs + (s + 8 * m + (L >> 1)) * XSTR + kk + q * 8);
            } else {
#pragma unroll
                for (int m = 0; m < 4; ++m)
                    a[m] = *(const short8*)(hin + (16 * m + L) * HSTR + (kk - 128) + q * 8);
            }
#pragma unroll
            for (int g = 0; g < 4; ++g)
#pragma unroll
                for (int m = 0; m < 4; ++m)
                    acc[m][g] = __builtin_amdgcn_mfma_f32_16x16x32_bf16(a[m], b[g], acc[m][g], 0, 0, 0);
        }

#pragma unroll
        for (int m = 0; m < 4; ++m)
#pragma unroll
            for (int e = 0; e < 2; ++e) {
                const int nl = 8 * m + q * 2 + e;
                if (nl < cnt) {
                    const int r0 = 2 * e, r1 = 2 * e + 1;
                    float iv = sigm(acc[m][0][r0] + acc[m][0][r1] + bias[ch]);
                    float ov = sigm(acc[m][1][r0] + acc[m][1][r1] + bias[128 + ch]);
                    float uv = ftanh(acc[m][2][r0] + acc[m][2][r1] + bias[256 + ch]);
                    float fl = sigm(acc[m][3][r0] + bias[384 + ch]);
                    float fr = sigm(acc[m][3][r1] + bias[384 + ch]);
                    float cl = cin[(2 * nl) * CSTR + ch];
                    float cr = cin[(2 * nl + 1) * CSTR + ch];
                    float cv = iv * uv + fl * cl + fr * cr;
                    cout[nl * CSTR + ch] = cv;
                    hout[nl * HSTR + ch] = f2bf(ov * ftanh(cv));
                }
            }
        __syncthreads();
        pp ^= 1;
    }

    // Projection: root h is row 0 of the last hout (== hping + pp*...).
    const unsigned short* hroot = hping + pp * 64 * HSTR;
    {
        const int o = tid & 127, sg = tid >> 7;
        float pacc = 0.f;
#pragma unroll
        for (int jj = 0; jj < 8; ++jj) {
            const int k = sg * 32 + jj * 4;
            float4 wv = *(const float4*)(Wp + o * DIM + k);
            pacc += bf2f(hroot[k]) * wv.x + bf2f(hroot[k + 1]) * wv.y +
                    bf2f(hroot[k + 2]) * wv.z + bf2f(hroot[k + 3]) * wv.w;
        }
        red[sg][o] = pacc;
    }
    __syncthreads();
    if (tid < 128) out[tid] = bWp[tid] + red[0][tid] + red[1][tid] + red[2][tid] + red[3][tid];
}

extern "C" void kernel_launch(void* const* d_in, const int* in_sizes, int n_in,
                              void* d_out, int out_size, void* d_ws, size_t ws_size,
                              hipStream_t stream) {
    const float* x   = (const float*)d_in[0];
    const float* Wi  = (const float*)d_in[2];  const float* bWi = (const float*)d_in[3];
    const float* Ui  = (const float*)d_in[4];  const float* bUi = (const float*)d_in[5];
    const float* Wf  = (const float*)d_in[6];  const float* bWf = (const float*)d_in[7];
    const float* Uf  = (const float*)d_in[8];  const float* bUf = (const float*)d_in[9];
    const float* Wo  = (const float*)d_in[10]; const float* bWo = (const float*)d_in[11];
    const float* Uo  = (const float*)d_in[12]; const float* bUo = (const float*)d_in[13];
    const float* Wu  = (const float*)d_in[14]; const float* bWu = (const float*)d_in[15];
    const float* Uu  = (const float*)d_in[16]; const float* bUu = (const float*)d_in[17];
    const float* Wp  = (const float*)d_in[18]; const float* bWp = (const float*)d_in[19];

    // ws: Bsw (131072 bf16 = 256 KB) | biasWU(512 f32) | biasL(512 f32) |
    //     cbuf (N*128 f32 = 64 MB) | hbf (N*128 bf16 = 32 MB)
    unsigned short* Bsw = (unsigned short*)d_ws;
    float* biasWU = (float*)(Bsw + 131072);
    float* biasL  = biasWU + 512;
    float* cbuf   = biasL + 512;
    unsigned short* hbf = (unsigned short*)(cbuf + (size_t)NTREE * DIM);

    WPtrs p;
    p.W[0] = Wi; p.W[1] = Wo; p.W[2] = Wu; p.W[3] = Wf;
    p.U[0] = Ui; p.U[1] = Uo; p.U[2] = Uu; p.U[3] = Uf;
    p.bW[0] = bWi; p.bW[1] = bWo; p.bW[2] = bWu; p.bW[3] = bWf;
    p.bU[0] = bUi; p.bU[1] = bUo; p.bU[2] = bUu; p.bU[3] = bUf;

    prep_kernel<<<512, 256, 0, stream>>>(p, Bsw, biasWU, biasL);

    leaf_kernel<<<(1 << (DEPTH - 1)) / 64, 512, 0, stream>>>(x, Bsw, biasL, hbf, cbuf);

    for (int d = DEPTH - 2; d >= 6; --d) {
        const int s = (1 << d) - 1;
        const int cnt = 1 << d;
        internal_kernel<<<cnt / 32, 512, 0, stream>>>(x, Bsw, biasWU, hbf, cbuf, s);
    }

    fused_all<<<1, 512, 0, stream>>>(x, Bsw, biasWU, hbf, cbuf, Wp, bWp, (float*)d_out);
}

// Round 6
// 298.149 us; speedup vs baseline: 3.1980x; 1.1129x over previous
//
#include <hip/hip_runtime.h>
#include <hip/hip_bf16.h>

// ChildSumTreeLSTM, complete binary tree heap layout (children of n: 2n+1, 2n+2).
// R6: epilogue stores assembled in LDS (aliased over dead stage buffers) then
// streamed as full coalesced rows -> kills the 4x partial-line write
// amplification seen in R5 (WRITE_SIZE 49MB vs 12.6 ideal at d=15).
// Template MT (m-tiles/wave): MT=4 (32 nodes/blk) for d=15, MT=2 (16 nodes/blk)
// for d<=14 to double grid width on mid levels. Leaf = 32 nodes/blk.
// Bsw = fragment-stream-ordered [W/2 | U] (f-gate W unhalved), gates [i,o,u,f];
// child row r computes [x_par; h_child]@B^T, epilogue sums row pairs in-lane.
// c fp32, h bf16.

#define DEPTH 17
#define NTREE ((1 << DEPTH) - 1)  // 131071
#define DIM 128
#define XSTR 136  // LDS stage strides (shorts)
#define HSTR 136
#define ASTR 132  // LDS assembly stride (floats); odd-ish mod 32 -> <=2-way on writes

typedef __attribute__((ext_vector_type(8))) short short8;
typedef __attribute__((ext_vector_type(4))) float float4v;

__device__ __forceinline__ float sigm(float v) {
    return __fdividef(1.0f, 1.0f + __expf(-v));
}
__device__ __forceinline__ float ftanh(float v) {
    v = fminf(15.0f, fmaxf(-15.0f, v));
    float e = __expf(2.0f * v);
    return __fdividef(e - 1.0f, e + 1.0f);
}

__device__ __forceinline__ unsigned short f2bf(float f) {
    union { float f; unsigned u; } a; a.f = f;
    unsigned u = a.u;
    return (unsigned short)((u + 0x7fffu + ((u >> 16) & 1u)) >> 16);  // RNE
}
__device__ __forceinline__ float bf2f(unsigned short s) {
    union { unsigned u; float f; } a; a.u = ((unsigned)s) << 16;
    return a.f;
}

struct WPtrs {
    const float* W[4];  const float* U[4];
    const float* bW[4]; const float* bU[4];
};

// Bsw[w][ks][g][lane][j] (w:8, ks:8, g:4, lane:64, j:8) = fragment-stream order.
// Element = B4[col = g*128 + w*16 + (lane&15)][k = ks*32 + (lane>>4)*8 + j],
// where B4 = [W * (g==3 ? 1 : 0.5) | U].
__global__ __launch_bounds__(256) void prep_kernel(WPtrs p, unsigned short* __restrict__ Bsw,
                                                   float* __restrict__ biasWU, float* __restrict__ biasL) {
    int idx = blockIdx.x * 256 + threadIdx.x;  // 0 .. 131071
    int j = idx & 7;
    int lane = (idx >> 3) & 63;
    int g = (idx >> 9) & 3;
    int ks = (idx >> 11) & 7;
    int w = idx >> 14;
    int L = lane & 15, q = lane >> 4;
    int c = w * 16 + L;
    int k = ks * 32 + q * 8 + j;
    float v = (k < 128) ? p.W[g][c * 128 + k] * (g == 3 ? 1.0f : 0.5f)
                        : p.U[g][c * 128 + (k - 128)];
    Bsw[idx] = f2bf(v);
    if (idx < 512) {
        int gg = idx >> 7, cc = idx & 127;
        biasWU[idx] = p.bW[gg][cc] + p.bU[gg][cc];
        biasL[idx]  = p.bW[gg][cc];
    }
}

// Stage `rows` fp32 x-rows (contiguous in global) into LDS bf16, stride XSTR.
__device__ __forceinline__ void stage_x(const float* __restrict__ x, unsigned short* xs,
                                        int nbase, int rows) {
    for (int c = threadIdx.x; c < rows * 32; c += 512) {
        int row = c >> 5, j = c & 31;
        float4 v = *(const float4*)(x + (size_t)(nbase + row) * DIM + j * 4);
        ushort4 o;
        o.x = f2bf(v.x); o.y = f2bf(v.y); o.z = f2bf(v.z); o.w = f2bf(v.w);
        *(ushort4*)(xs + row * XSTR + j * 4) = o;
    }
}

// Stage `rows` bf16 h-rows (contiguous in global) into LDS, stride HSTR.
__device__ __forceinline__ void stage_h(const unsigned short* __restrict__ hbf,
                                        unsigned short* hs, int cb, int rows) {
    for (int c = threadIdx.x; c < rows * 16; c += 512) {
        int row = c >> 4, j = c & 15;
        uint4 v = *(const uint4*)(hbf + (size_t)(cb + row) * DIM + j * 8);
        *(uint4*)(hs + row * HSTR + j * 8) = v;
    }
}

// Coalesced store of NPB assembled rows: c as float4, h converted to bf16.
__device__ __forceinline__ void store_rows(const float* csh, const float* hsh,
                                           float* __restrict__ cbuf,
                                           unsigned short* __restrict__ hbf,
                                           int nbase, int npb) {
    for (int i = threadIdx.x; i < npb * 32; i += 512) {
        int row = i >> 5, j = i & 31;
        *(float4*)(cbuf + (size_t)(nbase + row) * DIM + 4 * j) =
            *(const float4*)(csh + row * ASTR + 4 * j);
    }
    for (int i = threadIdx.x; i < npb * 32; i += 512) {
        int row = i >> 5, j = i & 31;
        float4 v = *(const float4*)(hsh + row * ASTR + 4 * j);
        ushort4 o;
        o.x = f2bf(v.x); o.y = f2bf(v.y); o.z = f2bf(v.z); o.w = f2bf(v.w);
        *(ushort4*)(hbf + (size_t)(nbase + row) * DIM + 4 * j) = o;
    }
}

// Internal level: NPB = 8*MT nodes/block (2*NPB child rows = MT m-tiles/wave).
// Wave w owns within-gate cols [16w,16w+16). C/D child-row = 16m+q*4+r, col = L.
template <int MT>
__global__ __launch_bounds__(512, 4) void internal_kernel(
    const float* __restrict__ x, const unsigned short* __restrict__ Bsw,
    const float* __restrict__ bias, unsigned short* __restrict__ hbf,
    float* __restrict__ cbuf, int s) {
    constexpr int NPB = 8 * MT;
    __shared__ __align__(16) unsigned char smem[NPB * ASTR * 4 * 2];
    unsigned short* xs = (unsigned short*)smem;                    // NPB*XSTR*2
    unsigned short* hs = (unsigned short*)(smem + NPB * XSTR * 2); // 2*NPB*HSTR*2
    float* csh = (float*)smem;                                     // NPB*ASTR*4
    float* hsh = (float*)(smem + NPB * ASTR * 4);                  // NPB*ASTR*4

    const int tid = threadIdx.x;
    const int w = tid >> 6, lane = tid & 63, L = lane & 15, q = lane >> 4;
    const int nbase = s + blockIdx.x * NPB;
    const int ch = w * 16 + L;

    stage_x(x, xs, nbase, NPB);
    stage_h(hbf, hs, 2 * nbase + 1, 2 * NPB);
    __syncthreads();

    // Prefetch child-c AFTER the barrier: lands during the MFMA loop.
    float cl[2 * MT], cr[2 * MT];
#pragma unroll
    for (int m = 0; m < MT; ++m)
#pragma unroll
        for (int e = 0; e < 2; ++e) {
            const int n = nbase + 8 * m + 2 * q + e;
            cl[m * 2 + e] = cbuf[(size_t)(2 * n + 1) * DIM + ch];
            cr[m * 2 + e] = cbuf[(size_t)(2 * n + 2) * DIM + ch];
        }

    float4v acc[MT][4];
#pragma unroll
    for (int m = 0; m < MT; ++m)
#pragma unroll
        for (int g = 0; g < 4; ++g) acc[m][g] = (float4v){0.f, 0.f, 0.f, 0.f};

    const unsigned short* bw = Bsw + ((size_t)w << 14) + lane * 8;

#pragma unroll
    for (int ks = 0; ks < 8; ++ks) {
        const int kk = ks * 32;
        short8 b[4];
#pragma unroll
        for (int g = 0; g < 4; ++g)
            b[g] = *(const short8*)(bw + ((ks * 4 + g) << 9));
        short8 a[MT];
        if (kk < 128) {  // x part: parent rows (lanes 2j,2j+1 broadcast)
#pragma unroll
            for (int m = 0; m < MT; ++m)
                a[m] = *(const short8*)(xs + (8 * m + (L >> 1)) * XSTR + kk + q * 8);
        } else {         // h part: child rows
#pragma unroll
            for (int m = 0; m < MT; ++m)
                a[m] = *(const short8*)(hs + (16 * m + L) * HSTR + (kk - 128) + q * 8);
        }
#pragma unroll
        for (int g = 0; g < 4; ++g)
#pragma unroll
            for (int m = 0; m < MT; ++m)
                acc[m][g] = __builtin_amdgcn_mfma_f32_16x16x32_bf16(a[m], b[g], acc[m][g], 0, 0, 0);
    }
    __syncthreads();  // stage buffers dead; safe to alias with assembly

#pragma unroll
    for (int m = 0; m < MT; ++m)
#pragma unroll
        for (int e = 0; e < 2; ++e) {
            const int nl = 8 * m + q * 2 + e;
            const int r0 = 2 * e, r1 = 2 * e + 1;
            float iv = sigm(acc[m][0][r0] + acc[m][0][r1] + bias[ch]);
            float ov = sigm(acc[m][1][r0] + acc[m][1][r1] + bias[128 + ch]);
            float uv = ftanh(acc[m][2][r0] + acc[m][2][r1] + bias[256 + ch]);
            float fl = sigm(acc[m][3][r0] + bias[384 + ch]);
            float fr = sigm(acc[m][3][r1] + bias[384 + ch]);
            float cv = iv * uv + fl * cl[m * 2 + e] + fr * cr[m * 2 + e];
            csh[nl * ASTR + ch] = cv;
            hsh[nl * ASTR + ch] = ov * ftanh(cv);
        }
    __syncthreads();

    store_rows(csh, hsh, cbuf, hbf, nbase, NPB);
}

// Leaf: 32 nodes/block, K=128 (x only), gates i,o,u (f skipped). logit = 2*acc + bW.
__global__ __launch_bounds__(512, 4) void leaf_kernel(
    const float* __restrict__ x, const unsigned short* __restrict__ Bsw,
    const float* __restrict__ bias, unsigned short* __restrict__ hbf,
    float* __restrict__ cbuf) {
    __shared__ __align__(16) unsigned char smem[32 * ASTR * 4 * 2];
    unsigned short* xs = (unsigned short*)smem;      // 32*XSTR*2
    float* csh = (float*)smem;                       // 32*ASTR*4
    float* hsh = (float*)(smem + 32 * ASTR * 4);     // 32*ASTR*4

    const int tid = threadIdx.x;
    const int w = tid >> 6, lane = tid & 63, L = lane & 15, q = lane >> 4;
    const int nbase = ((1 << (DEPTH - 1)) - 1) + blockIdx.x * 32;
    stage_x(x, xs, nbase, 32);
    __syncthreads();

    float4v acc[2][3];
#pragma unroll
    for (int m = 0; m < 2; ++m)
#pragma unroll
        for (int g = 0; g < 3; ++g) acc[m][g] = (float4v){0.f, 0.f, 0.f, 0.f};

    const unsigned short* bw = Bsw + ((size_t)w << 14) + lane * 8;

#pragma unroll
    for (int ks = 0; ks < 4; ++ks) {
        short8 b[3];
#pragma unroll
        for (int g = 0; g < 3; ++g)
            b[g] = *(const short8*)(bw + ((ks * 4 + g) << 9));
        short8 a[2];
#pragma unroll
        for (int m = 0; m < 2; ++m)
            a[m] = *(const short8*)(xs + (16 * m + L) * XSTR + ks * 32 + q * 8);
#pragma unroll
        for (int g = 0; g < 3; ++g)
#pragma unroll
            for (int m = 0; m < 2; ++m)
                acc[m][g] = __builtin_amdgcn_mfma_f32_16x16x32_bf16(a[m], b[g], acc[m][g], 0, 0, 0);
    }
    __syncthreads();

    const int ch = w * 16 + L;
#pragma unroll
    for (int m = 0; m < 2; ++m)
#pragma unroll
        for (int r = 0; r < 4; ++r) {
            const int nl = 16 * m + q * 4 + r;
            float iv = sigm(2.f * acc[m][0][r] + bias[ch]);
            float ov = sigm(2.f * acc[m][1][r] + bias[128 + ch]);
            float uv = ftanh(2.f * acc[m][2][r] + bias[256 + ch]);
            float cv = iv * uv;
            csh[nl * ASTR + ch] = cv;
            hsh[nl * ASTR + ch] = ov * ftanh(cv);
        }
    __syncthreads();

    store_rows(csh, hsh, cbuf, hbf, nbase, 32);
}

// Levels d=5..0 + projection, single 512-thread block, fully LDS-resident.
__global__ __launch_bounds__(512) void fused_all(
    const float* __restrict__ x, const unsigned short* __restrict__ Bsw,
    const float* __restrict__ bias, const unsigned short* __restrict__ hbf,
    const float* __restrict__ cbuf, const float* __restrict__ Wp,
    const float* __restrict__ bWp, float* __restrict__ out) {
    __shared__ __align__(16) unsigned short xs[63 * XSTR];
    __shared__ __align__(16) unsigned short hping[2 * 64 * HSTR];
    __shared__ __align__(16) float cping[2 * 64 * ASTR];
    __shared__ float red[4][128];
    const int tid = threadIdx.x;
    const int w = tid >> 6, lane = tid & 63, L = lane & 15, q = lane >> 4;
    const int ch = w * 16 + L;

    stage_x(x, xs, 0, 63);
    stage_h(hbf, hping, 63, 64);
    for (int c0 = tid; c0 < 64 * 32; c0 += 512) {
        int row = c0 >> 5, j = c0 & 31;
        float4 v = *(const float4*)(cbuf + (size_t)(63 + row) * DIM + j * 4);
        *(float4*)(cping + row * ASTR + j * 4) = v;
    }
    __syncthreads();

    int pp = 0;
    for (int d = 5; d >= 0; --d) {
        const int s = (1 << d) - 1, cnt = 1 << d;
        const unsigned short* hin = hping + pp * 64 * HSTR;
        const float* cin = cping + pp * 64 * ASTR;
        unsigned short* hout = hping + (1 - pp) * 64 * HSTR;
        float* cout = cping + (1 - pp) * 64 * ASTR;

        float4v acc[4][4];
#pragma unroll
        for (int m = 0; m < 4; ++m)
#pragma unroll
            for (int g = 0; g < 4; ++g) acc[m][g] = (float4v){0.f, 0.f, 0.f, 0.f};

        const unsigned short* bw = Bsw + ((size_t)w << 14) + lane * 8;

#pragma unroll
        for (int ks = 0; ks < 8; ++ks) {
            const int kk = ks * 32;
            short8 b[4];
#pragma unroll
            for (int g = 0; g < 4; ++g)
                b[g] = *(const short8*)(bw + ((ks * 4 + g) << 9));
            short8 a[4];
            if (kk < 128) {
#pragma unroll
                for (int m = 0; m < 4; ++m)
                    a[m] = *(const short8*)(xs + (s + 8 * m + (L >> 1)) * XSTR + kk + q * 8);
            } else {
#pragma unroll
                for (int m = 0; m < 4; ++m)
                    a[m] = *(const short8*)(hin + (16 * m + L) * HSTR + (kk - 128) + q * 8);
            }
#pragma unroll
            for (int g = 0; g < 4; ++g)
#pragma unroll
                for (int m = 0; m < 4; ++m)
                    acc[m][g] = __builtin_amdgcn_mfma_f32_16x16x32_bf16(a[m], b[g], acc[m][g], 0, 0, 0);
        }

#pragma unroll
        for (int m = 0; m < 4; ++m)
#pragma unroll
            for (int e = 0; e < 2; ++e) {
                const int nl = 8 * m + q * 2 + e;
                if (nl < cnt) {
                    const int r0 = 2 * e, r1 = 2 * e + 1;
                    float iv = sigm(acc[m][0][r0] + acc[m][0][r1] + bias[ch]);
                    float ov = sigm(acc[m][1][r0] + acc[m][1][r1] + bias[128 + ch]);
                    float uv = ftanh(acc[m][2][r0] + acc[m][2][r1] + bias[256 + ch]);
                    float fl = sigm(acc[m][3][r0] + bias[384 + ch]);
                    float fr = sigm(acc[m][3][r1] + bias[384 + ch]);
                    float cl = cin[(2 * nl) * ASTR + ch];
                    float cr = cin[(2 * nl + 1) * ASTR + ch];
                    float cv = iv * uv + fl * cl + fr * cr;
                    cout[nl * ASTR + ch] = cv;
                    hout[nl * HSTR + ch] = f2bf(ov * ftanh(cv));
                }
            }
        __syncthreads();
        pp ^= 1;
    }

    const unsigned short* hroot = hping + pp * 64 * HSTR;
    {
        const int o = tid & 127, sg = tid >> 7;
        float pacc = 0.f;
#pragma unroll
        for (int jj = 0; jj < 8; ++jj) {
            const int k = sg * 32 + jj * 4;
            float4 wv = *(const float4*)(Wp + o * DIM + k);
            pacc += bf2f(hroot[k]) * wv.x + bf2f(hroot[k + 1]) * wv.y +
                    bf2f(hroot[k + 2]) * wv.z + bf2f(hroot[k + 3]) * wv.w;
        }
        red[sg][o] = pacc;
    }
    __syncthreads();
    if (tid < 128) out[tid] = bWp[tid] + red[0][tid] + red[1][tid] + red[2][tid] + red[3][tid];
}

extern "C" void kernel_launch(void* const* d_in, const int* in_sizes, int n_in,
                              void* d_out, int out_size, void* d_ws, size_t ws_size,
                              hipStream_t stream) {
    const float* x   = (const float*)d_in[0];
    const float* Wi  = (const float*)d_in[2];  const float* bWi = (const float*)d_in[3];
    const float* Ui  = (const float*)d_in[4];  const float* bUi = (const float*)d_in[5];
    const float* Wf  = (const float*)d_in[6];  const float* bWf = (const float*)d_in[7];
    const float* Uf  = (const float*)d_in[8];  const float* bUf = (const float*)d_in[9];
    const float* Wo  = (const float*)d_in[10]; const float* bWo = (const float*)d_in[11];
    const float* Uo  = (const float*)d_in[12]; const float* bUo = (const float*)d_in[13];
    const float* Wu  = (const float*)d_in[14]; const float* bWu = (const float*)d_in[15];
    const float* Uu  = (const float*)d_in[16]; const float* bUu = (const float*)d_in[17];
    const float* Wp  = (const float*)d_in[18]; const float* bWp = (const float*)d_in[19];

    // ws: Bsw (131072 bf16 = 256 KB) | biasWU(512 f32) | biasL(512 f32) |
    //     cbuf (N*128 f32 = 64 MB) | hbf (N*128 bf16 = 32 MB)
    unsigned short* Bsw = (unsigned short*)d_ws;
    float* biasWU = (float*)(Bsw + 131072);
    float* biasL  = biasWU + 512;
    float* cbuf   = biasL + 512;
    unsigned short* hbf = (unsigned short*)(cbuf + (size_t)NTREE * DIM);

    WPtrs p;
    p.W[0] = Wi; p.W[1] = Wo; p.W[2] = Wu; p.W[3] = Wf;
    p.U[0] = Ui; p.U[1] = Uo; p.U[2] = Uu; p.U[3] = Uf;
    p.bW[0] = bWi; p.bW[1] = bWo; p.bW[2] = bWu; p.bW[3] = bWf;
    p.bU[0] = bUi; p.bU[1] = bUo; p.bU[2] = bUu; p.bU[3] = bUf;

    prep_kernel<<<512, 256, 0, stream>>>(p, Bsw, biasWU, biasL);

    leaf_kernel<<<(1 << (DEPTH - 1)) / 32, 512, 0, stream>>>(x, Bsw, biasL, hbf, cbuf);

    // d=15: 32 nodes/block (512 blocks = 2/CU); d=14..6: 16 nodes/block.
    internal_kernel<4><<<(1 << 15) / 32, 512, 0, stream>>>(x, Bsw, biasWU, hbf, cbuf, (1 << 15) - 1);
    for (int d = DEPTH - 3; d >= 6; --d) {
        const int s = (1 << d) - 1;
        const int cnt = 1 << d;
        internal_kernel<2><<<cnt / 16, 512, 0, stream>>>(x, Bsw, biasWU, hbf, cbuf, s);
    }

    fused_all<<<1, 512, 0, stream>>>(x, Bsw, biasWU, hbf, cbuf, Wp, bWp, (float*)d_out);
}

// Round 7
// 255.377 us; speedup vs baseline: 3.7336x; 1.1675x over previous
//
#include <hip/hip_runtime.h>
#include <hip/hip_bf16.h>

// ChildSumTreeLSTM, complete binary tree heap layout (children of n: 2n+1, 2n+2).
// R7: subtree-fused kernels. K1: 256 persistent blocks x 8 subtrees of
// 32 leaves (d16..d11, 63 nodes); intermediate h/c in LDS ping-pong, only x
// read + 1 root row written per subtree. B (all 4 gates, K=256, wave's 16-col
// slice) register-resident: 32 short8 = 128 VGPRs, loaded once per block.
// K2: 32 blocks, d10..d5, level-0 children from global. K3: 1 block, d4..d0 +
// projection. Bsw = fragment-stream-ordered [W/2 | U] (f-gate W unhalved),
// gates [i,o,u,f]; child row r computes [x_par; h_child]@B^T, epilogue sums
// row pairs in-lane. c fp32 (LDS/global), h bf16.

#define DEPTH 17
#define NTREE ((1 << DEPTH) - 1)  // 131071
#define DIM 128
#define XSTR 136  // LDS bf16 row stride (shorts): 272 B, stride%128B=16B -> 2-way max on b128
#define HSTR 136
#define CSTR 132  // LDS f32 row stride (floats); c accessed scalar per consecutive ch

typedef __attribute__((ext_vector_type(8))) short short8;
typedef __attribute__((ext_vector_type(4))) float float4v;

__device__ __forceinline__ float sigm(float v) {
    return __fdividef(1.0f, 1.0f + __expf(-v));
}
__device__ __forceinline__ float ftanh(float v) {
    v = fminf(15.0f, fmaxf(-15.0f, v));
    float e = __expf(2.0f * v);
    return __fdividef(e - 1.0f, e + 1.0f);
}

__device__ __forceinline__ unsigned short f2bf(float f) {
    union { float f; unsigned u; } a; a.f = f;
    unsigned u = a.u;
    return (unsigned short)((u + 0x7fffu + ((u >> 16) & 1u)) >> 16);  // RNE
}
__device__ __forceinline__ float bf2f(unsigned short s) {
    union { unsigned u; float f; } a; a.u = ((unsigned)s) << 16;
    return a.f;
}

struct WPtrs {
    const float* W[4];  const float* U[4];
    const float* bW[4]; const float* bU[4];
};

// Bsw[w][ks][g][lane][j] (w:8, ks:8, g:4, lane:64, j:8) = fragment-stream order.
// Element = B4[col = g*128 + w*16 + (lane&15)][k = ks*32 + (lane>>4)*8 + j],
// where B4 = [W * (g==3 ? 1 : 0.5) | U].
__global__ __launch_bounds__(256) void prep_kernel(WPtrs p, unsigned short* __restrict__ Bsw,
                                                   float* __restrict__ biasWU, float* __restrict__ biasL) {
    int idx = blockIdx.x * 256 + threadIdx.x;  // 0 .. 131071
    int j = idx & 7;
    int lane = (idx >> 3) & 63;
    int g = (idx >> 9) & 3;
    int ks = (idx >> 11) & 7;
    int w = idx >> 14;
    int L = lane & 15, q = lane >> 4;
    int c = w * 16 + L;
    int k = ks * 32 + q * 8 + j;
    float v = (k < 128) ? p.W[g][c * 128 + k] * (g == 3 ? 1.0f : 0.5f)
                        : p.U[g][c * 128 + (k - 128)];
    Bsw[idx] = f2bf(v);
    if (idx < 512) {
        int gg = idx >> 7, cc = idx & 127;
        biasWU[idx] = p.bW[gg][cc] + p.bU[gg][cc];
        biasL[idx]  = p.bW[gg][cc];
    }
}

// One internal level. Children h (MFMA A-frags) + c (epilogue) come from LDS
// (!GCH) or global rows starting at cb (GCH). x chunk in LDS (parent rows).
// cnt parent nodes -> 2*cnt child rows -> mt m-tiles, chunks of <=2.
template <bool GCH>
__device__ __forceinline__ void internal_level(
    const unsigned short* xc,
    const unsigned short* hin_l, const float* cin_l,
    const unsigned short* __restrict__ hin_g, const float* __restrict__ cin_g, long cb,
    unsigned short* ho, float* co, int cnt,
    const short8 (&b)[32], const float* __restrict__ biasWU,
    int L, int q, int ch) {
    const int rows = 2 * cnt;
    const int mt = (rows + 15) >> 4;
    for (int mc = 0; mc < mt; mc += 2) {
        const int mm_n = (mt - mc >= 2) ? 2 : 1;
        float4v acc[2][4];
#pragma unroll
        for (int mm = 0; mm < 2; ++mm)
#pragma unroll
            for (int g = 0; g < 4; ++g) acc[mm][g] = (float4v){0.f, 0.f, 0.f, 0.f};

#pragma unroll
        for (int ks = 0; ks < 8; ++ks) {
            const int kk = ks * 32;
            short8 a[2];
#pragma unroll
            for (int mm = 0; mm < 2; ++mm) {
                if (mm < mm_n) {
                    if (kk < 128) {
                        int xr = 8 * (mc + mm) + (L >> 1);
                        if (xr >= cnt) xr = 0;  // garbage row clamp (masked later)
                        a[mm] = *(const short8*)(xc + xr * XSTR + kk + q * 8);
                    } else if (!GCH) {
                        a[mm] = *(const short8*)(hin_l + (16 * (mc + mm) + L) * HSTR + (kk - 128) + q * 8);
                    } else {
                        a[mm] = *(const short8*)(hin_g + (size_t)(cb + 16 * (mc + mm) + L) * DIM + (kk - 128) + q * 8);
                    }
                }
            }
#pragma unroll
            for (int g = 0; g < 4; ++g)
#pragma unroll
                for (int mm = 0; mm < 2; ++mm)
                    if (mm < mm_n)
                        acc[mm][g] = __builtin_amdgcn_mfma_f32_16x16x32_bf16(a[mm], b[ks * 4 + g], acc[mm][g], 0, 0, 0);
        }

#pragma unroll
        for (int mm = 0; mm < 2; ++mm)
#pragma unroll
            for (int e = 0; e < 2; ++e) {
                if (mm < mm_n) {
                    const int nl = 8 * (mc + mm) + 2 * q + e;
                    if (nl < cnt) {
                        const int r0 = 2 * e, r1 = 2 * e + 1;
                        float iv = sigm(acc[mm][0][r0] + acc[mm][0][r1] + biasWU[ch]);
                        float ov = sigm(acc[mm][1][r0] + acc[mm][1][r1] + biasWU[128 + ch]);
                        float uv = ftanh(acc[mm][2][r0] + acc[mm][2][r1] + biasWU[256 + ch]);
                        float fl = sigm(acc[mm][3][r0] + biasWU[384 + ch]);
                        float fr = sigm(acc[mm][3][r1] + biasWU[384 + ch]);
                        float cl, cr;
                        if (!GCH) {
                            cl = cin_l[(2 * nl) * CSTR + ch];
                            cr = cin_l[(2 * nl + 1) * CSTR + ch];
                        } else {
                            cl = cin_g[(size_t)(cb + 2 * nl) * DIM + ch];
                            cr = cin_g[(size_t)(cb + 2 * nl + 1) * DIM + ch];
                        }
                        float cv = iv * uv + fl * cl + fr * cr;
                        co[nl * CSTR + ch] = cv;
                        ho[nl * HSTR + ch] = f2bf(ov * ftanh(cv));
                    }
                }
            }
    }
}

// True-leaf level: 32 nodes (2 m-tiles), K=128 (W half), gates i,o,u; logit = 2*acc + bW.
__device__ __forceinline__ void leaf_level(
    const unsigned short* xc, unsigned short* ho, float* co,
    const short8 (&b)[32], const float* __restrict__ biasL,
    int L, int q, int ch) {
    float4v acc[2][3];
#pragma unroll
    for (int mm = 0; mm < 2; ++mm)
#pragma unroll
        for (int g = 0; g < 3; ++g) acc[mm][g] = (float4v){0.f, 0.f, 0.f, 0.f};
#pragma unroll
    for (int ks = 0; ks < 4; ++ks) {
        short8 a[2];
        a[0] = *(const short8*)(xc + L * XSTR + ks * 32 + q * 8);
        a[1] = *(const short8*)(xc + (16 + L) * XSTR + ks * 32 + q * 8);
#pragma unroll
        for (int g = 0; g < 3; ++g)
#pragma unroll
            for (int mm = 0; mm < 2; ++mm)
                acc[mm][g] = __builtin_amdgcn_mfma_f32_16x16x32_bf16(a[mm], b[ks * 4 + g], acc[mm][g], 0, 0, 0);
    }
#pragma unroll
    for (int mm = 0; mm < 2; ++mm)
#pragma unroll
        for (int r = 0; r < 4; ++r) {
            const int nl = 16 * mm + q * 4 + r;
            float iv = sigm(2.f * acc[mm][0][r] + biasL[ch]);
            float ov = sigm(2.f * acc[mm][1][r] + biasL[128 + ch]);
            float uv = ftanh(2.f * acc[mm][2][r] + biasL[256 + ch]);
            float cv = iv * uv;
            co[nl * CSTR + ch] = cv;
            ho[nl * HSTR + ch] = f2bf(ov * ftanh(cv));
        }
}

// K1: persistent. 256 blocks x 8 subtrees; subtree = 32 leaves (d16) -> 1 node
// (d11, written to global). LDS: xs 63 rows, h/c ping-pong A(32)/B(16).
__global__ __launch_bounds__(512, 2) void k1_kernel(
    const float* __restrict__ x, const unsigned short* __restrict__ Bsw,
    const float* __restrict__ biasL, const float* __restrict__ biasWU,
    unsigned short* __restrict__ hbf, float* __restrict__ cbuf) {
    __shared__ __align__(16) unsigned short xs[63 * XSTR];
    __shared__ __align__(16) unsigned short hA[32 * HSTR];
    __shared__ __align__(16) unsigned short hB[16 * HSTR];
    __shared__ __align__(16) float cA[32 * CSTR];
    __shared__ __align__(16) float cB[16 * CSTR];

    const int tid = threadIdx.x;
    const int w = tid >> 6, lane = tid & 63, L = lane & 15, q = lane >> 4;
    const int ch = w * 16 + L;

    short8 b[32];
#pragma unroll
    for (int t = 0; t < 32; ++t)
        b[t] = *(const short8*)(Bsw + ((size_t)w << 14) + (t << 9) + lane * 8);

    for (int it = 0; it < 8; ++it) {
        const long t = (long)it * 256 + blockIdx.x;  // subtree index 0..2047
        // stage x for all 6 levels (contiguous rows per level)
        int xoff = 0;
#pragma unroll
        for (int l = 0; l < 6; ++l) {
            const int rows = 32 >> l;
            const long base = ((1 << (16 - l)) - 1) + t * rows;
            for (int i = tid; i < rows * 32; i += 512) {
                const int row = i >> 5, j = i & 31;
                float4 v = *(const float4*)(x + (size_t)(base + row) * DIM + j * 4);
                ushort4 o;
                o.x = f2bf(v.x); o.y = f2bf(v.y); o.z = f2bf(v.z); o.w = f2bf(v.w);
                *(ushort4*)(xs + (xoff + row) * XSTR + j * 4) = o;
            }
            xoff += rows;
        }
        __syncthreads();

        leaf_level(xs, hA, cA, b, biasL, L, q, ch);
        __syncthreads();

        const unsigned short* hin = hA;
        const float* cin = cA;
        xoff = 32;
#pragma unroll
        for (int l = 1; l < 6; ++l) {
            const int cnt = 32 >> l;
            unsigned short* ho = (l & 1) ? hB : hA;
            float* co = (l & 1) ? cB : cA;
            internal_level<false>(xs + xoff * XSTR, hin, cin, nullptr, nullptr, 0,
                                  ho, co, cnt, b, biasWU, L, q, ch);
            __syncthreads();
            hin = ho; cin = co; xoff += cnt;
        }

        // subtree root (d11 node 2047+t): c fp32 row + h bf16 row
        const long ob = (long)((1 << 11) - 1) + t;
        if (tid < 32)
            *(float4*)(cbuf + (size_t)ob * DIM + tid * 4) = *(const float4*)(cin + tid * 4);
        else if (tid < 48)
            *(uint4*)(hbf + (size_t)ob * DIM + (tid - 32) * 8) = *(const uint4*)(hin + (tid - 32) * 8);
        __syncthreads();
    }
}

// K2/K3: non-persistent fused subtree; level 0 children come from global rows
// [cb, cb+2C). K2: C=32, NL=6, d0=10 (32 blocks). K3: C=16, NL=5, d0=4, PROJ.
template <int C, int NL, bool PROJ>
__global__ __launch_bounds__(512, 2) void k23_kernel(
    const float* __restrict__ x, const unsigned short* __restrict__ Bsw,
    const float* __restrict__ biasWU, unsigned short* __restrict__ hbf,
    float* __restrict__ cbuf, int d0,
    const float* __restrict__ Wp, const float* __restrict__ bWp,
    float* __restrict__ out) {
    constexpr int TOTX = 2 * C - (C >> (NL - 1));
    constexpr int AR = (C < 16) ? 16 : C;
    __shared__ __align__(16) unsigned short xs[TOTX * XSTR];
    __shared__ __align__(16) unsigned short hA[AR * HSTR];
    __shared__ __align__(16) unsigned short hB[16 * HSTR];
    __shared__ __align__(16) float cA[AR * CSTR];
    __shared__ __align__(16) float cB[16 * CSTR];
    __shared__ float red[4][128];

    const int tid = threadIdx.x;
    const int w = tid >> 6, lane = tid & 63, L = lane & 15, q = lane >> 4;
    const int ch = w * 16 + L;

    short8 b[32];
#pragma unroll
    for (int t = 0; t < 32; ++t)
        b[t] = *(const short8*)(Bsw + ((size_t)w << 14) + (t << 9) + lane * 8);

    {
        int xoff = 0;
#pragma unroll
        for (int l = 0; l < NL; ++l) {
            const int rows = C >> l;
            const long base = ((1 << (d0 - l)) - 1) + (long)blockIdx.x * rows;
            for (int i = tid; i < rows * 32; i += 512) {
                const int row = i >> 5, j = i & 31;
                float4 v = *(const float4*)(x + (size_t)(base + row) * DIM + j * 4);
                ushort4 o;
                o.x = f2bf(v.x); o.y = f2bf(v.y); o.z = f2bf(v.z); o.w = f2bf(v.w);
                *(ushort4*)(xs + (xoff + row) * XSTR + j * 4) = o;
            }
            xoff += rows;
        }
    }
    __syncthreads();

    // level 0: children from global
    const long cb = ((1 << (d0 + 1)) - 1) + (long)blockIdx.x * (2 * C);
    internal_level<true>(xs, nullptr, nullptr, hbf, cbuf, cb,
                         hA, cA, C, b, biasWU, L, q, ch);
    __syncthreads();

    const unsigned short* hin = hA;
    const float* cin = cA;
    int xoff = C;
#pragma unroll
    for (int l = 1; l < NL; ++l) {
        const int cnt = C >> l;
        unsigned short* ho = (l & 1) ? hB : hA;
        float* co = (l & 1) ? cB : cA;
        internal_level<false>(xs + xoff * XSTR, hin, cin, nullptr, nullptr, 0,
                              ho, co, cnt, b, biasWU, L, q, ch);
        __syncthreads();
        hin = ho; cin = co; xoff += cnt;
    }

    if (PROJ) {
        const int o = tid & 127, sg = tid >> 7;
        float pacc = 0.f;
#pragma unroll
        for (int jj = 0; jj < 8; ++jj) {
            const int k = sg * 32 + jj * 4;
            float4 wv = *(const float4*)(Wp + o * DIM + k);
            pacc += bf2f(hin[k]) * wv.x + bf2f(hin[k + 1]) * wv.y +
                    bf2f(hin[k + 2]) * wv.z + bf2f(hin[k + 3]) * wv.w;
        }
        red[sg][o] = pacc;
        __syncthreads();
        if (tid < 128) out[tid] = bWp[tid] + red[0][tid] + red[1][tid] + red[2][tid] + red[3][tid];
    } else {
        const long ob = ((1 << (d0 - (NL - 1))) - 1) + (long)blockIdx.x;
        if (tid < 32)
            *(float4*)(cbuf + (size_t)ob * DIM + tid * 4) = *(const float4*)(cin + tid * 4);
        else if (tid < 48)
            *(uint4*)(hbf + (size_t)ob * DIM + (tid - 32) * 8) = *(const uint4*)(hin + (tid - 32) * 8);
    }
}

extern "C" void kernel_launch(void* const* d_in, const int* in_sizes, int n_in,
                              void* d_out, int out_size, void* d_ws, size_t ws_size,
                              hipStream_t stream) {
    const float* x   = (const float*)d_in[0];
    const float* Wi  = (const float*)d_in[2];  const float* bWi = (const float*)d_in[3];
    const float* Ui  = (const float*)d_in[4];  const float* bUi = (const float*)d_in[5];
    const float* Wf  = (const float*)d_in[6];  const float* bWf = (const float*)d_in[7];
    const float* Uf  = (const float*)d_in[8];  const float* bUf = (const float*)d_in[9];
    const float* Wo  = (const float*)d_in[10]; const float* bWo = (const float*)d_in[11];
    const float* Uo  = (const float*)d_in[12]; const float* bUo = (const float*)d_in[13];
    const float* Wu  = (const float*)d_in[14]; const float* bWu = (const float*)d_in[15];
    const float* Uu  = (const float*)d_in[16]; const float* bUu = (const float*)d_in[17];
    const float* Wp  = (const float*)d_in[18]; const float* bWp = (const float*)d_in[19];

    // ws: Bsw (131072 bf16 = 256 KB) | biasWU(512 f32) | biasL(512 f32) |
    //     cbuf (N*128 f32) | hbf (N*128 bf16)  (only rows < 4095 actually used)
    unsigned short* Bsw = (unsigned short*)d_ws;
    float* biasWU = (float*)(Bsw + 131072);
    float* biasL  = biasWU + 512;
    float* cbuf   = biasL + 512;
    unsigned short* hbf = (unsigned short*)(cbuf + (size_t)NTREE * DIM);

    WPtrs p;
    p.W[0] = Wi; p.W[1] = Wo; p.W[2] = Wu; p.W[3] = Wf;
    p.U[0] = Ui; p.U[1] = Uo; p.U[2] = Uu; p.U[3] = Uf;
    p.bW[0] = bWi; p.bW[1] = bWo; p.bW[2] = bWu; p.bW[3] = bWf;
    p.bU[0] = bUi; p.bU[1] = bUo; p.bU[2] = bUu; p.bU[3] = bUf;

    prep_kernel<<<512, 256, 0, stream>>>(p, Bsw, biasWU, biasL);

    // K1: d16..d11, 2048 subtrees of 32 leaves, 256 persistent blocks.
    k1_kernel<<<256, 512, 0, stream>>>(x, Bsw, biasL, biasWU, hbf, cbuf);
    // K2: d10..d5, 32 subtree blocks (children = K1's d11 rows).
    k23_kernel<32, 6, false><<<32, 512, 0, stream>>>(x, Bsw, biasWU, hbf, cbuf, 10,
                                                     nullptr, nullptr, nullptr);
    // K3: d4..d0 + projection (children = K2's d5 rows).
    k23_kernel<16, 5, true><<<1, 512, 0, stream>>>(x, Bsw, biasWU, hbf, cbuf, 4,
                                                   Wp, bWp, (float*)d_out);
}